// Round 7
// baseline (373.550 us; speedup 1.0000x reference)
//
#include <hip/hip_runtime.h>
#include <cstdint>
#include <cstddef>

#define H 1024
#define NB 8
#define S 2048
#define MROWS (NB*S)

using short8  = __attribute__((ext_vector_type(8))) short;
using ushort8 = __attribute__((ext_vector_type(8))) unsigned short;
using f32x4   = __attribute__((ext_vector_type(4))) float;

__device__ __forceinline__ unsigned short f2bf(float f){
  union { float f; unsigned int u; } c; c.f = f;
  unsigned int u = c.u;
  return (unsigned short)((u + 0x7fffu + ((u >> 16) & 1u)) >> 16);
}

// ---------------- small prep kernels ----------------

__global__ void k_cvt1(const float* __restrict__ src, unsigned short* __restrict__ dst){
  int i = (blockIdx.x * 256 + threadIdx.x) * 4;
  float4 v = *reinterpret_cast<const float4*>(src + i);
  ushort4 o;
  o.x = f2bf(v.x); o.y = f2bf(v.y); o.z = f2bf(v.z); o.w = f2bf(v.w);
  *reinterpret_cast<ushort4*>(dst + i) = o;
}

// transpose-and-cvt: dst[h,o] = bf16(src[o,h]), 64x64 tiles
__global__ __launch_bounds__(256) void k_transpose(const float* __restrict__ Wq_, const float* __restrict__ Wk_,
    unsigned short* __restrict__ Wqt_, unsigned short* __restrict__ Wkt_){
  const float* src = blockIdx.z ? Wk_ : Wq_;
  unsigned short* dst = blockIdx.z ? Wkt_ : Wqt_;
  __shared__ unsigned short tl[64][65];
  const int t = threadIdx.x;
  const int bx = blockIdx.x, by = blockIdx.y;
  const int co = (t & 15) * 4;
  #pragma unroll
  for (int pass = 0; pass < 4; ++pass){
    const int ro = (t >> 4) + pass * 16;
    float4 v = *reinterpret_cast<const float4*>(src + (size_t)(by*64 + ro) * H + bx*64 + co);
    tl[co + 0][ro] = f2bf(v.x);
    tl[co + 1][ro] = f2bf(v.y);
    tl[co + 2][ro] = f2bf(v.z);
    tl[co + 3][ro] = f2bf(v.w);
  }
  __syncthreads();
  #pragma unroll
  for (int pass = 0; pass < 4; ++pass){
    const int hh = (t >> 4) + pass * 16;
    const int oo = (t & 15) * 4;
    ushort4 w;
    w.x = tl[hh][oo + 0]; w.y = tl[hh][oo + 1]; w.z = tl[hh][oo + 2]; w.w = tl[hh][oo + 3];
    *reinterpret_cast<ushort4*>(dst + (size_t)(bx*64 + hh) * H + by*64 + oo) = w;
  }
}

// 4 GEMVs over big W: u[z][in] = sum_o W_z[o,in]*g_z[o]; partials [z][chunk8][1024]
__global__ void k_colproj(const float* __restrict__ Wq_, const float* __restrict__ Wk_,
                          const float* __restrict__ gqh, const float* __restrict__ gkh,
                          const float* __restrict__ bq, const float* __restrict__ bk,
                          float* __restrict__ up4){
  const int z = blockIdx.z;
  const float* W = (z == 0 || z == 2) ? Wq_ : Wk_;
  const float* g = (z == 0) ? gqh : (z == 1) ? gkh : (z == 2) ? bk : bq;
  const int in = blockIdx.x * 256 + threadIdx.x;
  const int o0 = blockIdx.y * 128;
  float s = 0.f;
  for (int o = 0; o < 128; ++o) s = fmaf(W[(size_t)(o0 + o) * H + in], g[o0 + o], s);
  up4[(z * 8 + blockIdx.y) * 1024 + in] = s;
}

__global__ void k_ucombine4(const float* __restrict__ up4, float* __restrict__ u4){
  int i = blockIdx.x * 256 + threadIdx.x;
  int z = i >> 10, h = i & 1023;
  float s = 0.f;
  #pragma unroll
  for (int c = 0; c < 8; ++c) s += up4[(z * 8 + c) * 1024 + h];
  u4[i] = s;
}

__global__ __launch_bounds__(256) void k_ctxproj(const float* __restrict__ Wcq, const float* __restrict__ Wck,
    const float* __restrict__ ctx, float* __restrict__ outq, float* __restrict__ outk){
  __shared__ float cs[NB * H];
  const float* W = blockIdx.y ? Wck : Wcq;
  float* out = blockIdx.y ? outk : outq;
  const int t = threadIdx.x;
  for (int i = t; i < NB * H; i += 256) cs[i] = ctx[i];
  __syncthreads();
  const int wid = t >> 6, lane = t & 63;
  const int row = blockIdx.x * 4 + wid;
  float a[NB];
  #pragma unroll
  for (int b = 0; b < NB; ++b) a[b] = 0.f;
  for (int i0 = 0; i0 < H; i0 += 64){
    const float w = W[(size_t)row * H + i0 + lane];
    #pragma unroll
    for (int b = 0; b < NB; ++b) a[b] = fmaf(w, cs[b * H + i0 + lane], a[b]);
  }
  #pragma unroll
  for (int b = 0; b < NB; ++b){
    float v = a[b];
    #pragma unroll
    for (int off = 32; off > 0; off >>= 1) v += __shfl_xor(v, off);
    if (lane == 0) out[b * H + row] = v;
  }
}

__global__ __launch_bounds__(256) void k_colproj8(const float* __restrict__ Wq_, const float* __restrict__ Wk_,
    const float* __restrict__ ctxq, const float* __restrict__ ctxk, float* __restrict__ up8){
  __shared__ float cs[NB * 128];
  const int z = blockIdx.z;
  const float* W = z ? Wk_ : Wq_;
  const float* g = z ? ctxq : ctxk;
  const int t = threadIdx.x;
  const int o0 = blockIdx.y * 128;
  for (int i = t; i < NB * 128; i += 256){
    int b = i >> 7, oo = i & 127;
    cs[i] = g[b * H + o0 + oo];
  }
  __syncthreads();
  const int h = blockIdx.x * 256 + t;
  float s[NB];
  #pragma unroll
  for (int b = 0; b < NB; ++b) s[b] = 0.f;
  for (int oo = 0; oo < 128; ++oo){
    const float w = W[(size_t)(o0 + oo) * H + h];
    #pragma unroll
    for (int b = 0; b < NB; ++b) s[b] = fmaf(w, cs[b * 128 + oo], s[b]);
  }
  #pragma unroll
  for (int b = 0; b < NB; ++b)
    up8[z * 65536 + blockIdx.y * 8192 + b * 1024 + h] = s[b];
}

__global__ void k_ucombine8(const float* __restrict__ up8, float* __restrict__ uXY){
  int i = blockIdx.x * 256 + threadIdx.x;
  int z = i >> 13, rem = i & 8191;
  float s = 0.f;
  #pragma unroll
  for (int y = 0; y < 8; ++y) s += up8[z * 65536 + y * 8192 + rem];
  uXY[i] = s;
}

__global__ __launch_bounds__(512) void k_scalars(const float* __restrict__ bq, const float* __restrict__ gqh,
    const float* __restrict__ bk, const float* __restrict__ gkh,
    const float* __restrict__ ctx, const float* __restrict__ gqc, const float* __restrict__ gkc,
    const float* __restrict__ ctxq, const float* __restrict__ ctxk, float* __restrict__ scal){
  const int wid = threadIdx.x >> 6, lane = threadIdx.x & 63;
  for (int d = wid; d < 43; d += 8){
    const float *pa, *pb;
    if (d == 0){ pa = bq; pb = gqh; }
    else if (d == 1){ pa = bk; pb = gkh; }
    else if (d < 10){ pa = ctx + (d - 2) * H; pb = gqc; }
    else if (d < 18){ pa = ctx + (d - 10) * H; pb = gkc; }
    else if (d == 18){ pa = bq; pb = bk; }
    else if (d < 27){ pa = bq; pb = ctxk + (d - 19) * H; }
    else if (d < 35){ pa = ctxq + (d - 27) * H; pb = bk; }
    else { pa = ctxq + (d - 35) * H; pb = ctxk + (d - 35) * H; }
    float s = 0.f;
    for (int i = lane; i < H; i += 64) s = fmaf(pa[i], pb[i], s);
    #pragma unroll
    for (int off = 32; off > 0; off >>= 1) s += __shfl_xor(s, off);
    if (lane == 0) scal[d] = s;
  }
}

// hs f32 -> bf16, 6 per-row dots -> P/Q gate-reconstruction arrays (float4 each)
__global__ __launch_bounds__(256) void k_prepass(const float* __restrict__ hs,
    const float* __restrict__ u4, const float* __restrict__ uXY, const float* __restrict__ scal,
    unsigned short* __restrict__ hsb, float* __restrict__ Prow, float* __restrict__ Qcol){
  const int t = threadIdx.x, wid = t >> 6, lane = t & 63;
  const int row = blockIdx.x * 4 + wid;
  const int b = row >> 11;
  const float* hrow = hs + (size_t)row * H;
  const float* u_q = u4;
  const float* u_k = u4 + 1024;
  const float* aq  = u4 + 2048;
  const float* ak  = u4 + 3072;
  const float* uXb = uXY + b * 1024;
  const float* uYb = uXY + 8192 + b * 1024;
  unsigned short* orow = hsb + (size_t)row * H;
  float d1 = 0.f, d2 = 0.f, d3 = 0.f, d4 = 0.f, d5 = 0.f, d6 = 0.f;
  #pragma unroll
  for (int c = 0; c < 4; ++c){
    const int idx = (lane + c * 64) * 4;
    float4 v  = *reinterpret_cast<const float4*>(hrow + idx);
    float4 a1 = *reinterpret_cast<const float4*>(u_q + idx);
    float4 a2 = *reinterpret_cast<const float4*>(u_k + idx);
    float4 a3 = *reinterpret_cast<const float4*>(aq + idx);
    float4 a4 = *reinterpret_cast<const float4*>(ak + idx);
    float4 a5 = *reinterpret_cast<const float4*>(uXb + idx);
    float4 a6 = *reinterpret_cast<const float4*>(uYb + idx);
    ushort4 o; o.x = f2bf(v.x); o.y = f2bf(v.y); o.z = f2bf(v.z); o.w = f2bf(v.w);
    *reinterpret_cast<ushort4*>(orow + idx) = o;
    d1 += v.x*a1.x + v.y*a1.y + v.z*a1.z + v.w*a1.w;
    d2 += v.x*a2.x + v.y*a2.y + v.z*a2.z + v.w*a2.w;
    d3 += v.x*a3.x + v.y*a3.y + v.z*a3.z + v.w*a3.w;
    d4 += v.x*a4.x + v.y*a4.y + v.z*a4.z + v.w*a4.w;
    d5 += v.x*a5.x + v.y*a5.y + v.z*a5.z + v.w*a5.w;
    d6 += v.x*a6.x + v.y*a6.y + v.z*a6.z + v.w*a6.w;
  }
  #pragma unroll
  for (int off = 32; off > 0; off >>= 1){
    d1 += __shfl_xor(d1, off); d2 += __shfl_xor(d2, off); d3 += __shfl_xor(d3, off);
    d4 += __shfl_xor(d4, off); d5 += __shfl_xor(d5, off); d6 += __shfl_xor(d6, off);
  }
  if (lane == 0){
    float gqv = 1.f / (1.f + __expf(-(d1 + scal[0] + scal[2 + b])));
    float gkv = 1.f / (1.f + __expf(-(d2 + scal[1] + scal[10 + b])));
    float X = d5 + scal[19 + b];
    float Y = d6 + scal[27 + b];
    float eq = 1.f - gqv, ek = 1.f - gkv;
    float4 P; P.x = eq; P.y = eq * (d3 + scal[18]); P.z = eq * X; P.w = gqv;
    float4 Q; Q.x = ek; Q.y = ek * d4; Q.z = gkv; Q.w = ek * Y + gkv * scal[35 + b];
    reinterpret_cast<float4*>(Prow)[row] = P;
    reinterpret_cast<float4*>(Qcol)[row] = Q;
  }
}

// ---------------- 256x256 8-phase GEMM (bt form: C[i,j] = sum_k A[i,k]*B[j,k]) ----------------
// MODE 0: plain bf16 out                 (T = hs @ M)
// MODE 2: V = hs@Wv^T+bv, store transposed -> bf16 Vt[b][h][s]
// MODE 3: scores with gate reconstruction  -> f32 d_out (gate=Prow, ctxv=Qcol)
// MODE 4: plain f32 out                  (M split-K partials; PV output)

#define STG(bufi, opi, halfi, koff, P0, P1) \
  do { __builtin_amdgcn_global_load_lds((const __attribute__((address_space(1))) void*)(P0 + (koff)), \
      (__attribute__((address_space(3))) void*)((char*)(&lds[bufi][opi][halfi][0]) + (wid*2+0)*1024), 16, 0, 0); \
    __builtin_amdgcn_global_load_lds((const __attribute__((address_space(1))) void*)(P1 + (koff)), \
      (__attribute__((address_space(3))) void*)((char*)(&lds[bufi][opi][halfi][0]) + (wid*2+1)*1024), 16, 0, 0); } while(0)
#define STG_A(bufi, halfi, koff) STG(bufi, 0, halfi, koff, sA0, sA1)
#define STG_B(bufi, halfi, koff) STG(bufi, 1, halfi, koff, sB0, sB1)

#define DS_A(bufi, ks, mh) \
  do { _Pragma("unroll") for (int m_ = 0; m_ < 4; ++m_){ \
      const int ar_ = wr*128 + ((mh)*4 + m_)*16 + (lane & 15); \
      const int sl_ = (lane >> 4) ^ ((ar_ >> 1) & 3); \
      af[m_] = *reinterpret_cast<const short8*>(&lds[bufi][0][ks][ar_*32 + sl_*8]); } } while(0)
#define DS_B(bufi, ks) \
  do { _Pragma("unroll") for (int n_ = 0; n_ < 4; ++n_){ \
      const int br_ = wc*64 + n_*16 + (lane & 15); \
      const int sl_ = (lane >> 4) ^ ((br_ >> 1) & 3); \
      bf[n_] = *reinterpret_cast<const short8*>(&lds[bufi][1][ks][br_*32 + sl_*8]); } } while(0)
#define MFMA16(mh) \
  do { __builtin_amdgcn_s_setprio(1); \
    _Pragma("unroll") for (int m_ = 0; m_ < 4; ++m_) \
      _Pragma("unroll") for (int n_ = 0; n_ < 4; ++n_) \
        acc[(mh)*4 + m_][n_] = __builtin_amdgcn_mfma_f32_16x16x32_bf16(af[m_], bf[n_], acc[(mh)*4 + m_][n_], 0, 0, 0); \
    __builtin_amdgcn_s_setprio(0); } while(0)
#define VM4() do { asm volatile("s_waitcnt vmcnt(4)" ::: "memory"); } while(0)
#define VM0() do { asm volatile("s_waitcnt vmcnt(0)" ::: "memory"); } while(0)
#define BAR() do { asm volatile("" ::: "memory"); __builtin_amdgcn_s_barrier(); asm volatile("" ::: "memory"); } while(0)
#define LGKM0() do { asm volatile("s_waitcnt lgkmcnt(0)" ::: "memory"); __builtin_amdgcn_sched_barrier(0); } while(0)

template<int MODE>
__global__ __launch_bounds__(512, 2)
void k_gemm(const unsigned short* __restrict__ A, const unsigned short* __restrict__ B,
            int K, int ldA, int ldB, long long Abatch, long long Bbatch,
            const float* __restrict__ gate, const float* __restrict__ bias,
            const float* __restrict__ ctxv,
            unsigned short* __restrict__ outb, float* __restrict__ outf,
            long long outBatch, float scale)
{
  // [buf][op A=0,B=1][khalf][256 rows * 4 slots * 8 bf16] = 128 KiB total
  __shared__ __align__(16) short lds[2][2][2][8192];

  const int t = threadIdx.x;
  const int wid = t >> 6, lane = t & 63;
  const int wr = wid >> 2, wc = wid & 3;      // 2 x 4 wave grid

  // bijective XCD swizzle (all our grids have nwg % 8 == 0)
  const int gx = gridDim.x, gy = gridDim.y;
  const int nwg = gx * gy * gridDim.z;
  const int lin = blockIdx.x + gx * (blockIdx.y + gy * blockIdx.z);
  const int nlin = (lin & 7) * (nwg >> 3) + (lin >> 3);
  const int bxs = nlin % gx;
  const int rs_ = nlin / gx;
  const int bys = rs_ % gy;
  const int bz  = rs_ / gy;

  const unsigned short* Ab = A + (size_t)bz * (size_t)Abatch;
  const unsigned short* Bb = B + (size_t)bz * (size_t)Bbatch;
  const int row0 = bxs * 256;
  const int col0 = bys * 256;

  // staging constants: thread's 2 chunks within a 16KB half (256 rows x 4 slots of 16B)
  const int c0 = (wid*2 + 0)*64 + lane;
  const int c1 = (wid*2 + 1)*64 + lane;
  const int r0s = c0 >> 2, r1s = c1 >> 2;
  const int kc0 = (c0 & 3) ^ ((r0s >> 1) & 3);   // pre-swizzled global k-chunk (involution)
  const int kc1 = (c1 & 3) ^ ((r1s >> 1) & 3);
  const unsigned short* sA0 = Ab + (size_t)(row0 + r0s) * (size_t)ldA + kc0*8;
  const unsigned short* sA1 = Ab + (size_t)(row0 + r1s) * (size_t)ldA + kc1*8;
  const unsigned short* sB0 = Bb + (size_t)(col0 + r0s) * (size_t)ldB + kc0*8;
  const unsigned short* sB1 = Bb + (size_t)(col0 + r1s) * (size_t)ldB + kc1*8;

  f32x4 acc[8][4] = {};
  short8 af[4], bf[4];

  // prologue: stage tile 0 into buf0 (4 halves), drain, barrier
  STG_A(0, 0, 0); STG_B(0, 0, 0); STG_A(0, 1, 32); STG_B(0, 1, 32);
  VM0(); BAR();

  const int niter = K >> 7;       // 2 K-tiles (of 64) per iteration
  for (int it = 0; it < niter; ++it){
    const int t1k = (it*2 + 1) << 6;
    const int t2k = (it*2 + 2) << 6;
    const bool more = (it + 1 < niter);
    DS_A(0, 0, 0); DS_B(0, 0); STG_A(1, 0, t1k);      BAR(); LGKM0(); MFMA16(0);                              BAR();
    DS_A(0, 0, 1);             STG_B(1, 0, t1k);      BAR(); LGKM0(); MFMA16(1); VM4();                       BAR();
    DS_A(0, 1, 0); DS_B(0, 1); STG_A(1, 1, t1k + 32); BAR(); LGKM0(); MFMA16(0);                              BAR();
    DS_A(0, 1, 1);             STG_B(1, 1, t1k + 32); BAR(); LGKM0(); MFMA16(1); if (more) { VM4(); } else { VM0(); } BAR();
    DS_A(1, 0, 0); DS_B(1, 0); if (more) { STG_A(0, 0, t2k); }      BAR(); LGKM0(); MFMA16(0);                BAR();
    DS_A(1, 0, 1);             if (more) { STG_B(0, 0, t2k); }      BAR(); LGKM0(); MFMA16(1); if (more) { VM4(); } BAR();
    DS_A(1, 1, 0); DS_B(1, 1); if (more) { STG_A(0, 1, t2k + 32); } BAR(); LGKM0(); MFMA16(0);                BAR();
    DS_A(1, 1, 1);             if (more) { STG_B(0, 1, t2k + 32); } BAR(); LGKM0(); MFMA16(1); if (more) { VM4(); } BAR();
  }

  // ---- epilogues ---- (C/D layout m89: col=lane&15, row=(lane>>4)*4+reg)
  if constexpr (MODE == 0){
    // LDS-bounce -> 16B coalesced bf16 stores, two 128-row rounds
    unsigned short* tp = (unsigned short*)lds;   // [128][264]
    #pragma unroll
    for (int ci = 0; ci < 2; ++ci){
      __syncthreads();
      if (wr == ci){
        #pragma unroll
        for (int mi = 0; mi < 8; ++mi)
          #pragma unroll
          for (int n = 0; n < 4; ++n)
            #pragma unroll
            for (int r = 0; r < 4; ++r){
              const int lr = mi*16 + (lane >> 4)*4 + r;
              const int lc = wc*64 + n*16 + (lane & 15);
              tp[lr*264 + lc] = f2bf(acc[mi][n][r]);
            }
      }
      __syncthreads();
      const int rr = t & 127;
      const int cc = (t >> 7) * 64;
      const unsigned short* srcp = tp + rr*264 + cc;
      unsigned short* dst = outb + (size_t)(row0 + ci*128 + rr) * H + col0 + cc;
      #pragma unroll
      for (int i = 0; i < 64; i += 8)
        *reinterpret_cast<ushort8*>(dst + i) = *reinterpret_cast<const ushort8*>(srcp + i);
    }
  } else if constexpr (MODE == 2){
    // transposed store: write [h][s] LDS quadrants, then 64B-contiguous global stores
    unsigned short* tp = (unsigned short*)lds;   // [128 h][136 s]
    const int bb = row0 >> 11;
    const int s0 = row0 & (S - 1);
    #pragma unroll
    for (int ci = 0; ci < 2; ++ci)
      #pragma unroll
      for (int cj = 0; cj < 2; ++cj){
        __syncthreads();
        if (wr == ci && (wc >> 1) == cj){
          const int lc0 = (wc & 1) * 64;
          #pragma unroll
          for (int mi = 0; mi < 8; ++mi)
            #pragma unroll
            for (int n = 0; n < 4; ++n)
              #pragma unroll
              for (int r = 0; r < 4; ++r){
                const int lr = mi*16 + (lane >> 4)*4 + r;           // s
                const int lc = lc0 + n*16 + (lane & 15);            // h
                tp[lc*136 + lr] = f2bf(acc[mi][n][r] + bias[col0 + cj*128 + lc]);
              }
        }
        __syncthreads();
        const int hh = t & 127;
        const int sc = (t >> 7) * 32;
        const unsigned short* srcp = tp + hh*136 + sc;
        unsigned short* vout = outb + (size_t)bb * H * S + (size_t)(col0 + cj*128 + hh) * S
                                    + (size_t)(s0 + ci*128 + sc);
        #pragma unroll
        for (int i2 = 0; i2 < 32; i2 += 8)
          *reinterpret_cast<ushort8*>(vout + i2) = *reinterpret_cast<const ushort8*>(srcp + i2);
      }
  } else if constexpr (MODE == 3){
    // stage P (rows) and Q (cols) float4 arrays into LDS
    float* PQ = (float*)lds;     // P1..P4 at [0..1023], Q1..Q4 at [1024..2047]
    __syncthreads();
    if (t < 256){
      float4 p = reinterpret_cast<const float4*>(gate)[(size_t)bz * S + row0 + t];
      PQ[t] = p.x; PQ[256 + t] = p.y; PQ[512 + t] = p.z; PQ[768 + t] = p.w;
    } else if (t < 512){
      const int j = t - 256;
      float4 q = reinterpret_cast<const float4*>(ctxv)[(size_t)bz * S + col0 + j];
      PQ[1024 + j] = q.x; PQ[1280 + j] = q.y; PQ[1536 + j] = q.z; PQ[1792 + j] = q.w;
    }
    __syncthreads();
    float q1[4], q2[4], q3[4], q4[4];
    #pragma unroll
    for (int n = 0; n < 4; ++n){
      const int lc = wc*64 + n*16 + (lane & 15);
      q1[n] = PQ[1024 + lc]; q2[n] = PQ[1280 + lc]; q3[n] = PQ[1536 + lc]; q4[n] = PQ[1792 + lc];
    }
    #pragma unroll
    for (int mi = 0; mi < 8; ++mi)
      #pragma unroll
      for (int r = 0; r < 4; ++r){
        const int lr = wr*128 + mi*16 + (lane >> 4)*4 + r;
        const float p1 = PQ[lr], p2 = PQ[256 + lr], p3 = PQ[512 + lr], p4 = PQ[768 + lr];
        #pragma unroll
        for (int n = 0; n < 4; ++n){
          const int gcol = col0 + wc*64 + n*16 + (lane & 15);
          const float g = acc[mi][n][r];
          const float val = q1[n] * fmaf(p1, g, p2) + p1 * q2[n] + p3 * q3[n] + p4 * q4[n];
          outf[(size_t)bz * (size_t)outBatch + (size_t)(row0 + lr) * S + gcol] = scale * val;
        }
      }
  } else {
    #pragma unroll
    for (int mi = 0; mi < 8; ++mi)
      #pragma unroll
      for (int n = 0; n < 4; ++n)
        #pragma unroll
        for (int r = 0; r < 4; ++r){
          const int grow = row0 + wr*128 + mi*16 + (lane >> 4)*4 + r;
          const int gcol = col0 + wc*64 + n*16 + (lane & 15);
          outf[(size_t)bz * (size_t)outBatch + (size_t)grow * H + gcol] = acc[mi][n][r];
        }
  }
}

// reduce 4 split-K partials -> Mt bf16
__global__ void k_mreduce(const float* __restrict__ mpart, unsigned short* __restrict__ Mt){
  const int i4 = (blockIdx.x * 256 + threadIdx.x) * 4;
  float4 s = *reinterpret_cast<const float4*>(mpart + i4);
  #pragma unroll
  for (int kz = 1; kz < 4; ++kz){
    float4 p = *reinterpret_cast<const float4*>(mpart + (size_t)kz * 1048576 + i4);
    s.x += p.x; s.y += p.y; s.z += p.z; s.w += p.w;
  }
  ushort4 o; o.x = f2bf(s.x); o.y = f2bf(s.y); o.z = f2bf(s.z); o.w = f2bf(s.w);
  *reinterpret_cast<ushort4*>(Mt + i4) = o;
}

// ---------------- softmax ----------------
__global__ __launch_bounds__(256) void k_softmax(const float* __restrict__ scores,
                                                 unsigned short* __restrict__ probs){
  const int row = blockIdx.x;
  const float* srow = scores + (size_t)row * S;
  unsigned short* prow = probs + (size_t)row * S;
  const int t = threadIdx.x, wid = t >> 6, lane = t & 63;
  __shared__ float red[8];
  float4 v0 = *reinterpret_cast<const float4*>(srow + t * 4);
  float4 v1 = *reinterpret_cast<const float4*>(srow + 1024 + t * 4);
  float m = fmaxf(fmaxf(fmaxf(v0.x, v0.y), fmaxf(v0.z, v0.w)),
                  fmaxf(fmaxf(v1.x, v1.y), fmaxf(v1.z, v1.w)));
  #pragma unroll
  for (int off = 32; off > 0; off >>= 1) m = fmaxf(m, __shfl_xor(m, off));
  if (lane == 0) red[wid] = m;
  __syncthreads();
  m = fmaxf(fmaxf(red[0], red[1]), fmaxf(red[2], red[3]));
  float4 e0, e1;
  e0.x = __expf(v0.x - m); e0.y = __expf(v0.y - m); e0.z = __expf(v0.z - m); e0.w = __expf(v0.w - m);
  e1.x = __expf(v1.x - m); e1.y = __expf(v1.y - m); e1.z = __expf(v1.z - m); e1.w = __expf(v1.w - m);
  float s = (e0.x + e0.y + e0.z + e0.w) + (e1.x + e1.y + e1.z + e1.w);
  #pragma unroll
  for (int off = 32; off > 0; off >>= 1) s += __shfl_xor(s, off);
  if (lane == 0) red[4 + wid] = s;
  __syncthreads();
  s = (red[4] + red[5]) + (red[6] + red[7]);
  const float inv = 1.f / s;
  ushort4 o;
  o.x = f2bf(e0.x * inv); o.y = f2bf(e0.y * inv); o.z = f2bf(e0.z * inv); o.w = f2bf(e0.w * inv);
  *reinterpret_cast<ushort4*>(prow + t * 4) = o;
  o.x = f2bf(e1.x * inv); o.y = f2bf(e1.y * inv); o.z = f2bf(e1.z * inv); o.w = f2bf(e1.w * inv);
  *reinterpret_cast<ushort4*>(prow + 1024 + t * 4) = o;
}

// ---------------- launch ----------------
extern "C" void kernel_launch(void* const* d_in, const int* in_sizes, int n_in,
                              void* d_out, int out_size, void* d_ws, size_t ws_size,
                              hipStream_t stream) {
  const float* hs  = (const float*)d_in[0];
  const float* ctx = (const float*)d_in[1];
  const float* Wq  = (const float*)d_in[2];
  const float* bq  = (const float*)d_in[3];
  const float* Wk  = (const float*)d_in[4];
  const float* bk  = (const float*)d_in[5];
  const float* Wv  = (const float*)d_in[6];
  const float* bv  = (const float*)d_in[7];
  const float* Wcq = (const float*)d_in[8];
  const float* Wck = (const float*)d_in[9];
  const float* gqh = (const float*)d_in[10];
  const float* gkh = (const float*)d_in[11];
  const float* gqc = (const float*)d_in[12];
  const float* gkc = (const float*)d_in[13];

  char* ws = (char*)d_ws;
  unsigned short* hsb  = (unsigned short*)(ws);                    // 33.5 MB
  unsigned short* Tb   = (unsigned short*)(ws + 33554432);         // 33.5 MB
  unsigned short* vt   = (unsigned short*)(ws + 67108864);         // 33.5 MB
  unsigned short* wvb  = (unsigned short*)(ws + 100663296);        // 2 MB
  unsigned short* wqt  = (unsigned short*)(ws + 102760448);        // 2 MB
  unsigned short* wkt  = (unsigned short*)(ws + 104857600);        // 2 MB
  unsigned short* mt   = (unsigned short*)(ws + 106954752);        // 2 MB
  float* mpart = (float*)(ws + 109051904);                         // 16.8 MB
  float* up4   = (float*)(ws + 125829120);                         // 128 KB
  float* u4    = (float*)(ws + 125960192);                         // 16 KB
  float* up8   = (float*)(ws + 125976576);                         // 512 KB
  float* uXY   = (float*)(ws + 126500864);                         // 64 KB
  float* ctxq  = (float*)(ws + 126566400);                         // 32 KB
  float* ctxk  = (float*)(ws + 126599168);                         // 32 KB
  float* scal  = (float*)(ws + 126631936);                         // 256 B
  float* Prow  = (float*)(ws + 126632192);                         // 256 KB
  float* Qcol  = (float*)(ws + 126894336);                         // 256 KB
  unsigned short* probs = (unsigned short*)ws;   // 67 MB over hsb+Tb (both dead post-scores)

  float* out_attn   = (float*)d_out;                        // [NB,S,H]
  float* out_scores = out_attn + (size_t)MROWS * H;         // [NB,S,S]

  // prep
  k_transpose<<<dim3(16, 16, 2), 256, 0, stream>>>(Wq, Wk, wqt, wkt);
  k_cvt1<<<1024, 256, 0, stream>>>(Wv, wvb);
  k_ctxproj<<<dim3(256, 2), 256, 0, stream>>>(Wcq, Wck, ctx, ctxq, ctxk);
  k_colproj<<<dim3(4, 8, 4), 256, 0, stream>>>(Wq, Wk, gqh, gkh, bq, bk, up4);
  k_ucombine4<<<16, 256, 0, stream>>>(up4, u4);
  k_colproj8<<<dim3(4, 8, 2), 256, 0, stream>>>(Wq, Wk, ctxq, ctxk, up8);
  k_ucombine8<<<64, 256, 0, stream>>>(up8, uXY);
  k_scalars<<<1, 512, 0, stream>>>(bq, gqh, bk, gkh, ctx, gqc, gkc, ctxq, ctxk, scal);
  k_prepass<<<MROWS / 4, 256, 0, stream>>>(hs, u4, uXY, scal, hsb, Prow, Qcol);

  // Mt[j,h] = sum_o Wk[o,j]*Wq[o,h]: split-K=4 partials via MODE 4, then reduce
  k_gemm<4><<<dim3(4, 4, 4), 512, 0, stream>>>(wkt, wqt, 256, 1024, 1024, 256, 256,
      nullptr, nullptr, nullptr, nullptr, mpart, 1048576LL, 1.f);
  k_mreduce<<<1024, 256, 0, stream>>>(mpart, mt);

  // T = hs @ M  (M=16384, N=1024, K=1024), bf16 out
  k_gemm<0><<<dim3(64, 4, 1), 512, 0, stream>>>(hsb, mt, 1024, 1024, 1024, 0, 0,
      nullptr, nullptr, nullptr, Tb, nullptr, 0, 1.f);

  // V = hs@Wv^T + bv, stored transposed
  k_gemm<2><<<dim3(64, 4, 1), 512, 0, stream>>>(hsb, wvb, 1024, 1024, 1024, 0, 0,
      nullptr, bv, nullptr, vt, nullptr, 0, 1.f);

  // scores = gate-reconstruct(T @ hs^T) * scale  (per batch M=N=2048, K=1024), f32 to d_out
  k_gemm<3><<<dim3(8, 8, 8), 512, 0, stream>>>(Tb, hsb, 1024, 1024, 1024,
      (long long)S * H, (long long)S * H, Prow, nullptr, Qcol,
      nullptr, out_scores, (long long)S * S, 0.03125f);

  // softmax -> probs bf16
  k_softmax<<<MROWS, 256, 0, stream>>>(out_scores, probs);

  // output = probs @ V (per batch M=2048, N=1024, K=2048; B operand = Vt)
  k_gemm<4><<<dim3(8, 4, 8), 512, 0, stream>>>(probs, vt, 2048, 2048, 2048,
      (long long)S * S, (long long)H * S, nullptr, nullptr, nullptr,
      nullptr, out_attn, (long long)S * H, 1.f);
}

// Round 8
// 369.730 us; speedup vs baseline: 1.0103x; 1.0103x over previous
//
#include <hip/hip_runtime.h>
#include <cstdint>
#include <cstddef>

#define H 1024
#define NB 8
#define S 2048
#define MROWS (NB*S)

using short8  = __attribute__((ext_vector_type(8))) short;
using ushort8 = __attribute__((ext_vector_type(8))) unsigned short;
using f32x4   = __attribute__((ext_vector_type(4))) float;

__device__ __forceinline__ unsigned short f2bf(float f){
  union { float f; unsigned int u; } c; c.f = f;
  unsigned int u = c.u;
  return (unsigned short)((u + 0x7fffu + ((u >> 16) & 1u)) >> 16);
}

// ---------------- small prep kernels ----------------

// Wq/Wk/Wv f32 -> bf16 (one dispatch)
__global__ void k_cvt3(const float* __restrict__ a, const float* __restrict__ b, const float* __restrict__ c,
                       unsigned short* __restrict__ oa, unsigned short* __restrict__ ob, unsigned short* __restrict__ oc){
  const float* src = blockIdx.y == 0 ? a : (blockIdx.y == 1 ? b : c);
  unsigned short* dst = blockIdx.y == 0 ? oa : (blockIdx.y == 1 ? ob : oc);
  int i = (blockIdx.x * 256 + threadIdx.x) * 4;
  float4 v = *reinterpret_cast<const float4*>(src + i);
  ushort4 o;
  o.x = f2bf(v.x); o.y = f2bf(v.y); o.z = f2bf(v.z); o.w = f2bf(v.w);
  *reinterpret_cast<ushort4*>(dst + i) = o;
}

// u[z][in] = sum_o W_z[o,in]*g_z[o]; partials [z][chunk8][1024]
__global__ void k_colproj(const float* __restrict__ Wq_, const float* __restrict__ Wk_,
                          const float* __restrict__ gqh, const float* __restrict__ gkh,
                          float* __restrict__ up){
  const int z = blockIdx.z;
  const float* W = z ? Wk_ : Wq_;
  const float* g = z ? gkh : gqh;
  const int in = blockIdx.x * 256 + threadIdx.x;
  const int o0 = blockIdx.y * 128;
  float s = 0.f;
  for (int o = 0; o < 128; ++o) s = fmaf(W[(size_t)(o0 + o) * H + in], g[o0 + o], s);
  up[(z * 8 + blockIdx.y) * 1024 + in] = s;
}

__global__ void k_ucombine(const float* __restrict__ up, float* __restrict__ u2){
  int i = blockIdx.x * 256 + threadIdx.x;   // 0..2047
  int z = i >> 10, h = i & 1023;
  float s = 0.f;
  #pragma unroll
  for (int c = 0; c < 8; ++c) s += up[(z * 8 + c) * 1024 + h];
  u2[i] = s;
}

// out[b*H + row] = sum_in Wc[row,in] * ctx[b,in]
__global__ __launch_bounds__(256) void k_ctxproj(const float* __restrict__ Wcq, const float* __restrict__ Wck,
    const float* __restrict__ ctx, float* __restrict__ outq, float* __restrict__ outk){
  __shared__ float cs[NB * H];
  const float* W = blockIdx.y ? Wck : Wcq;
  float* out = blockIdx.y ? outk : outq;
  const int t = threadIdx.x;
  for (int i = t; i < NB * H; i += 256) cs[i] = ctx[i];
  __syncthreads();
  const int wid = t >> 6, lane = t & 63;
  const int row = blockIdx.x * 4 + wid;
  float a[NB];
  #pragma unroll
  for (int b = 0; b < NB; ++b) a[b] = 0.f;
  for (int i0 = 0; i0 < H; i0 += 64){
    const float w = W[(size_t)row * H + i0 + lane];
    #pragma unroll
    for (int b = 0; b < NB; ++b) a[b] = fmaf(w, cs[b * H + i0 + lane], a[b]);
  }
  #pragma unroll
  for (int b = 0; b < NB; ++b){
    float v = a[b];
    #pragma unroll
    for (int off = 32; off > 0; off >>= 1) v += __shfl_xor(v, off);
    if (lane == 0) out[b * H + row] = v;
  }
}

// 18 scalar dots: [0]=bq.gqh [1]=bk.gkh [2+b]=ctx_b.gqc [10+b]=ctx_b.gkc
__global__ __launch_bounds__(512) void k_scalars(const float* __restrict__ bq, const float* __restrict__ gqh,
    const float* __restrict__ bk, const float* __restrict__ gkh,
    const float* __restrict__ ctx, const float* __restrict__ gqc, const float* __restrict__ gkc,
    float* __restrict__ scal){
  const int wid = threadIdx.x >> 6, lane = threadIdx.x & 63;
  for (int d = wid; d < 18; d += 8){
    const float *pa, *pb;
    if (d == 0){ pa = bq; pb = gqh; }
    else if (d == 1){ pa = bk; pb = gkh; }
    else if (d < 10){ pa = ctx + (d - 2) * H; pb = gqc; }
    else { pa = ctx + (d - 10) * H; pb = gkc; }
    float s = 0.f;
    for (int i = lane; i < H; i += 64) s = fmaf(pa[i], pb[i], s);
    #pragma unroll
    for (int off = 32; off > 0; off >>= 1) s += __shfl_xor(s, off);
    if (lane == 0) scal[d] = s;
  }
}

// hs f32 -> bf16, fp32-exact gates per row
__global__ __launch_bounds__(256) void k_prepass(const float* __restrict__ hs,
    const float* __restrict__ u2, const float* __restrict__ scal,
    unsigned short* __restrict__ hsb, float* __restrict__ gq, float* __restrict__ gk){
  const int t = threadIdx.x, wid = t >> 6, lane = t & 63;
  const int row = blockIdx.x * 4 + wid;
  const float* hrow = hs + (size_t)row * H;
  const float* u_q = u2;
  const float* u_k = u2 + 1024;
  unsigned short* orow = hsb + (size_t)row * H;
  float sq = 0.f, sk = 0.f;
  #pragma unroll
  for (int c = 0; c < 4; ++c){
    const int idx = (lane + c * 64) * 4;
    float4 v  = *reinterpret_cast<const float4*>(hrow + idx);
    float4 uq = *reinterpret_cast<const float4*>(u_q + idx);
    float4 uk = *reinterpret_cast<const float4*>(u_k + idx);
    ushort4 o; o.x = f2bf(v.x); o.y = f2bf(v.y); o.z = f2bf(v.z); o.w = f2bf(v.w);
    *reinterpret_cast<ushort4*>(orow + idx) = o;
    sq += v.x*uq.x + v.y*uq.y + v.z*uq.z + v.w*uq.w;
    sk += v.x*uk.x + v.y*uk.y + v.z*uk.z + v.w*uk.w;
  }
  #pragma unroll
  for (int off = 32; off > 0; off >>= 1){
    sq += __shfl_xor(sq, off);
    sk += __shfl_xor(sk, off);
  }
  if (lane == 0){
    const int b = row >> 11;
    gq[row] = 1.f / (1.f + __expf(-(sq + scal[0] + scal[2 + b])));
    gk[row] = 1.f / (1.f + __expf(-(sk + scal[1] + scal[10 + b])));
  }
}

// ---------------- 256x256 8-phase GEMM (bt form: C[i,j] = sum_k A[i,k]*B[j,k]) ----------------
// MODE 0: gated bf16 out (Qhat/Khat projections; gate, bias, ctxv used)
// MODE 2: V = hs@Wv^T+bv, store transposed -> bf16 Vt[b][h][s]
// MODE 3: scores = A@B^T * scale -> f32 d_out
// MODE 4: plain f32 out (PV)

#define STG(bufi, opi, halfi, koff, P0, P1) \
  do { __builtin_amdgcn_global_load_lds((const __attribute__((address_space(1))) void*)(P0 + (koff)), \
      (__attribute__((address_space(3))) void*)((char*)(&lds[bufi][opi][halfi][0]) + (wid*2+0)*1024), 16, 0, 0); \
    __builtin_amdgcn_global_load_lds((const __attribute__((address_space(1))) void*)(P1 + (koff)), \
      (__attribute__((address_space(3))) void*)((char*)(&lds[bufi][opi][halfi][0]) + (wid*2+1)*1024), 16, 0, 0); } while(0)
#define STG_A(bufi, halfi, koff) STG(bufi, 0, halfi, koff, sA0, sA1)
#define STG_B(bufi, halfi, koff) STG(bufi, 1, halfi, koff, sB0, sB1)

#define DS_A(bufi, ks, mh) \
  do { _Pragma("unroll") for (int m_ = 0; m_ < 4; ++m_){ \
      const int ar_ = wr*128 + ((mh)*4 + m_)*16 + (lane & 15); \
      const int sl_ = (lane >> 4) ^ ((ar_ >> 1) & 3); \
      af[m_] = *reinterpret_cast<const short8*>(&lds[bufi][0][ks][ar_*32 + sl_*8]); } } while(0)
#define DS_B(bufi, ks) \
  do { _Pragma("unroll") for (int n_ = 0; n_ < 4; ++n_){ \
      const int br_ = wc*64 + n_*16 + (lane & 15); \
      const int sl_ = (lane >> 4) ^ ((br_ >> 1) & 3); \
      bf[n_] = *reinterpret_cast<const short8*>(&lds[bufi][1][ks][br_*32 + sl_*8]); } } while(0)
#define MFMA16(mh) \
  do { __builtin_amdgcn_s_setprio(1); \
    _Pragma("unroll") for (int m_ = 0; m_ < 4; ++m_) \
      _Pragma("unroll") for (int n_ = 0; n_ < 4; ++n_) \
        acc[(mh)*4 + m_][n_] = __builtin_amdgcn_mfma_f32_16x16x32_bf16(af[m_], bf[n_], acc[(mh)*4 + m_][n_], 0, 0, 0); \
    __builtin_amdgcn_s_setprio(0); } while(0)
#define VM4() do { asm volatile("s_waitcnt vmcnt(4)" ::: "memory"); } while(0)
#define VM0() do { asm volatile("s_waitcnt vmcnt(0)" ::: "memory"); } while(0)
#define BAR() do { asm volatile("" ::: "memory"); __builtin_amdgcn_s_barrier(); asm volatile("" ::: "memory"); } while(0)
#define LGKM0() do { asm volatile("s_waitcnt lgkmcnt(0)" ::: "memory"); __builtin_amdgcn_sched_barrier(0); } while(0)

template<int MODE>
__global__ __launch_bounds__(512, 2)
void k_gemm(const unsigned short* __restrict__ A, const unsigned short* __restrict__ B,
            int K, int ldA, int ldB, long long Abatch, long long Bbatch,
            const float* __restrict__ gate, const float* __restrict__ bias,
            const float* __restrict__ ctxv,
            unsigned short* __restrict__ outb, float* __restrict__ outf,
            long long outBatch, float scale)
{
  // [buf][op A=0,B=1][khalf][256 rows * 4 slots * 8 bf16] = 128 KiB total
  __shared__ __align__(16) short lds[2][2][2][8192];

  const int t = threadIdx.x;
  const int wid = t >> 6, lane = t & 63;
  const int wr = wid >> 2, wc = wid & 3;      // 2 x 4 wave grid
  const int bz = blockIdx.z;
  const unsigned short* Ab = A + (size_t)bz * (size_t)Abatch;
  const unsigned short* Bb = B + (size_t)bz * (size_t)Bbatch;
  const int row0 = blockIdx.x * 256;
  const int col0 = blockIdx.y * 256;

  // staging constants: thread's 2 chunks within a 16KB half (256 rows x 4 slots of 16B)
  const int c0 = (wid*2 + 0)*64 + lane;
  const int c1 = (wid*2 + 1)*64 + lane;
  const int r0s = c0 >> 2, r1s = c1 >> 2;
  const int kc0 = (c0 & 3) ^ ((r0s >> 1) & 3);   // pre-swizzled global k-chunk (involution)
  const int kc1 = (c1 & 3) ^ ((r1s >> 1) & 3);
  const unsigned short* sA0 = Ab + (size_t)(row0 + r0s) * (size_t)ldA + kc0*8;
  const unsigned short* sA1 = Ab + (size_t)(row0 + r1s) * (size_t)ldA + kc1*8;
  const unsigned short* sB0 = Bb + (size_t)(col0 + r0s) * (size_t)ldB + kc0*8;
  const unsigned short* sB1 = Bb + (size_t)(col0 + r1s) * (size_t)ldB + kc1*8;

  f32x4 acc[8][4] = {};
  short8 af[4], bf[4];

  // prologue: stage tile 0 into buf0 (4 halves), drain, barrier
  STG_A(0, 0, 0); STG_B(0, 0, 0); STG_A(0, 1, 32); STG_B(0, 1, 32);
  VM0(); BAR();

  const int niter = K >> 7;       // 2 K-tiles (of 64) per iteration
  for (int it = 0; it < niter; ++it){
    const int t1k = (it*2 + 1) << 6;
    const int t2k = (it*2 + 2) << 6;
    const bool more = (it + 1 < niter);
    DS_A(0, 0, 0); DS_B(0, 0); STG_A(1, 0, t1k);      BAR(); LGKM0(); MFMA16(0);                              BAR();
    DS_A(0, 0, 1);             STG_B(1, 0, t1k);      BAR(); LGKM0(); MFMA16(1); VM4();                       BAR();
    DS_A(0, 1, 0); DS_B(0, 1); STG_A(1, 1, t1k + 32); BAR(); LGKM0(); MFMA16(0);                              BAR();
    DS_A(0, 1, 1);             STG_B(1, 1, t1k + 32); BAR(); LGKM0(); MFMA16(1); if (more) { VM4(); } else { VM0(); } BAR();
    DS_A(1, 0, 0); DS_B(1, 0); if (more) { STG_A(0, 0, t2k); }      BAR(); LGKM0(); MFMA16(0);                BAR();
    DS_A(1, 0, 1);             if (more) { STG_B(0, 0, t2k); }      BAR(); LGKM0(); MFMA16(1); if (more) { VM4(); } BAR();
    DS_A(1, 1, 0); DS_B(1, 1); if (more) { STG_A(0, 1, t2k + 32); } BAR(); LGKM0(); MFMA16(0);                BAR();
    DS_A(1, 1, 1);             if (more) { STG_B(0, 1, t2k + 32); } BAR(); LGKM0(); MFMA16(1); if (more) { VM4(); } BAR();
  }

  // ---- epilogues ---- (C/D layout m89: col=lane&15, row=(lane>>4)*4+reg)
  if constexpr (MODE == 0){
    // gated projection: out = (1-g)*(acc+bias) + g*ctx, LDS-bounce -> 16B stores
    unsigned short* tp = (unsigned short*)lds;          // [128][264] = 67584 B
    float* gl = (float*)((char*)lds + 69632);           // gate rows [256]
    float* bl = gl + 256;                                // bias cols [256]
    float* cl = bl + 256;                                // ctx  cols [256]
    const int b = row0 >> 11;
    __syncthreads();
    if (t < 256){
      gl[t] = gate[row0 + t];
      bl[t] = bias[col0 + t];
      cl[t] = ctxv[b * H + col0 + t];
    }
    __syncthreads();
    #pragma unroll
    for (int ci = 0; ci < 2; ++ci){
      if (ci) __syncthreads();
      if (wr == ci){
        #pragma unroll
        for (int mi = 0; mi < 8; ++mi)
          #pragma unroll
          for (int r = 0; r < 4; ++r){
            const int lr = mi*16 + (lane >> 4)*4 + r;
            const float g = gl[ci*128 + lr];
            #pragma unroll
            for (int n = 0; n < 4; ++n){
              const int lc = wc*64 + n*16 + (lane & 15);
              const float q = acc[mi][n][r] + bl[lc];
              tp[lr*264 + lc] = f2bf((1.f - g) * q + g * cl[lc]);
            }
          }
      }
      __syncthreads();
      const int rr = t & 127;
      const int cc = (t >> 7) * 64;
      const unsigned short* srcp = tp + rr*264 + cc;
      unsigned short* dst = outb + (size_t)(row0 + ci*128 + rr) * H + col0 + cc;
      #pragma unroll
      for (int i = 0; i < 64; i += 8)
        *reinterpret_cast<ushort8*>(dst + i) = *reinterpret_cast<const ushort8*>(srcp + i);
    }
  } else if constexpr (MODE == 2){
    // transposed store: write [h][s] LDS quadrants, then 64B-contiguous global stores
    unsigned short* tp = (unsigned short*)lds;   // [128 h][136 s]
    const int bb = row0 >> 11;
    const int s0 = row0 & (S - 1);
    #pragma unroll
    for (int ci = 0; ci < 2; ++ci)
      #pragma unroll
      for (int cj = 0; cj < 2; ++cj){
        __syncthreads();
        if (wr == ci && (wc >> 1) == cj){
          const int lc0 = (wc & 1) * 64;
          #pragma unroll
          for (int mi = 0; mi < 8; ++mi)
            #pragma unroll
            for (int n = 0; n < 4; ++n)
              #pragma unroll
              for (int r = 0; r < 4; ++r){
                const int lr = mi*16 + (lane >> 4)*4 + r;           // s
                const int lc = lc0 + n*16 + (lane & 15);            // h
                tp[lc*136 + lr] = f2bf(acc[mi][n][r] + bias[col0 + cj*128 + lc]);
              }
        }
        __syncthreads();
        const int hh = t & 127;
        const int sc = (t >> 7) * 32;
        const unsigned short* srcp = tp + hh*136 + sc;
        unsigned short* vout = outb + (size_t)bb * H * S + (size_t)(col0 + cj*128 + hh) * S
                                    + (size_t)(s0 + ci*128 + sc);
        #pragma unroll
        for (int i2 = 0; i2 < 32; i2 += 8)
          *reinterpret_cast<ushort8*>(vout + i2) = *reinterpret_cast<const ushort8*>(srcp + i2);
      }
  } else if constexpr (MODE == 3){
    #pragma unroll
    for (int mi = 0; mi < 8; ++mi)
      #pragma unroll
      for (int n = 0; n < 4; ++n)
        #pragma unroll
        for (int r = 0; r < 4; ++r){
          const int grow = row0 + wr*128 + mi*16 + (lane >> 4)*4 + r;
          const int gcol = col0 + wc*64 + n*16 + (lane & 15);
          outf[(size_t)bz * (size_t)outBatch + (size_t)grow * S + gcol] = acc[mi][n][r] * scale;
        }
  } else {
    #pragma unroll
    for (int mi = 0; mi < 8; ++mi)
      #pragma unroll
      for (int n = 0; n < 4; ++n)
        #pragma unroll
        for (int r = 0; r < 4; ++r){
          const int grow = row0 + wr*128 + mi*16 + (lane >> 4)*4 + r;
          const int gcol = col0 + wc*64 + n*16 + (lane & 15);
          outf[(size_t)bz * (size_t)outBatch + (size_t)grow * H + gcol] = acc[mi][n][r];
        }
  }
}

// ---------------- softmax ----------------
__global__ __launch_bounds__(256) void k_softmax(const float* __restrict__ scores,
                                                 unsigned short* __restrict__ probs){
  const int row = blockIdx.x;
  const float* srow = scores + (size_t)row * S;
  unsigned short* prow = probs + (size_t)row * S;
  const int t = threadIdx.x, wid = t >> 6, lane = t & 63;
  __shared__ float red[8];
  float4 v0 = *reinterpret_cast<const float4*>(srow + t * 4);
  float4 v1 = *reinterpret_cast<const float4*>(srow + 1024 + t * 4);
  float m = fmaxf(fmaxf(fmaxf(v0.x, v0.y), fmaxf(v0.z, v0.w)),
                  fmaxf(fmaxf(v1.x, v1.y), fmaxf(v1.z, v1.w)));
  #pragma unroll
  for (int off = 32; off > 0; off >>= 1) m = fmaxf(m, __shfl_xor(m, off));
  if (lane == 0) red[wid] = m;
  __syncthreads();
  m = fmaxf(fmaxf(red[0], red[1]), fmaxf(red[2], red[3]));
  float4 e0, e1;
  e0.x = __expf(v0.x - m); e0.y = __expf(v0.y - m); e0.z = __expf(v0.z - m); e0.w = __expf(v0.w - m);
  e1.x = __expf(v1.x - m); e1.y = __expf(v1.y - m); e1.z = __expf(v1.z - m); e1.w = __expf(v1.w - m);
  float s = (e0.x + e0.y + e0.z + e0.w) + (e1.x + e1.y + e1.z + e1.w);
  #pragma unroll
  for (int off = 32; off > 0; off >>= 1) s += __shfl_xor(s, off);
  if (lane == 0) red[4 + wid] = s;
  __syncthreads();
  s = (red[4] + red[5]) + (red[6] + red[7]);
  const float inv = 1.f / s;
  ushort4 o;
  o.x = f2bf(e0.x * inv); o.y = f2bf(e0.y * inv); o.z = f2bf(e0.z * inv); o.w = f2bf(e0.w * inv);
  *reinterpret_cast<ushort4*>(prow + t * 4) = o;
  o.x = f2bf(e1.x * inv); o.y = f2bf(e1.y * inv); o.z = f2bf(e1.z * inv); o.w = f2bf(e1.w * inv);
  *reinterpret_cast<ushort4*>(prow + 1024 + t * 4) = o;
}

// ---------------- launch ----------------
extern "C" void kernel_launch(void* const* d_in, const int* in_sizes, int n_in,
                              void* d_out, int out_size, void* d_ws, size_t ws_size,
                              hipStream_t stream) {
  const float* hs  = (const float*)d_in[0];
  const float* ctx = (const float*)d_in[1];
  const float* Wq  = (const float*)d_in[2];
  const float* bq  = (const float*)d_in[3];
  const float* Wk  = (const float*)d_in[4];
  const float* bk  = (const float*)d_in[5];
  const float* Wv  = (const float*)d_in[6];
  const float* bv  = (const float*)d_in[7];
  const float* Wcq = (const float*)d_in[8];
  const float* Wck = (const float*)d_in[9];
  const float* gqh = (const float*)d_in[10];
  const float* gkh = (const float*)d_in[11];
  const float* gqc = (const float*)d_in[12];
  const float* gkc = (const float*)d_in[13];

  char* ws = (char*)d_ws;    // ~768 MB available
  unsigned short* hsb   = (unsigned short*)(ws);                   // 33.5 MB
  unsigned short* qhat  = (unsigned short*)(ws + 33554432);        // 33.5 MB
  unsigned short* khat  = (unsigned short*)(ws + 67108864);        // 33.5 MB
  unsigned short* vt    = (unsigned short*)(ws + 100663296);       // 33.5 MB
  unsigned short* probs = (unsigned short*)(ws + 134217728);       // 33.5 MB
  unsigned short* wqb   = (unsigned short*)(ws + 167772160);       // 2 MB
  unsigned short* wkb   = (unsigned short*)(ws + 169869312);       // 2 MB
  unsigned short* wvb   = (unsigned short*)(ws + 171966464);       // 2 MB
  float* up    = (float*)(ws + 174063616);                         // 64 KB
  float* u2    = (float*)(ws + 174129152);                         // 8 KB
  float* ctxq  = (float*)(ws + 174137344);                         // 32 KB
  float* ctxk  = (float*)(ws + 174170112);                         // 32 KB
  float* gq    = (float*)(ws + 174202880);                         // 64 KB
  float* gk    = (float*)(ws + 174268416);                         // 64 KB
  float* scal  = (float*)(ws + 174333952);                         // 256 B

  float* out_attn   = (float*)d_out;                        // [NB,S,H]
  float* out_scores = out_attn + (size_t)MROWS * H;         // [NB,S,S]

  // prep (6 dispatches)
  k_cvt3<<<dim3(1024, 3), 256, 0, stream>>>(Wq, Wk, Wv, wqb, wkb, wvb);
  k_colproj<<<dim3(4, 8, 2), 256, 0, stream>>>(Wq, Wk, gqh, gkh, up);
  k_ucombine<<<8, 256, 0, stream>>>(up, u2);
  k_ctxproj<<<dim3(256, 2), 256, 0, stream>>>(Wcq, Wck, ctx, ctxq, ctxk);
  k_scalars<<<1, 512, 0, stream>>>(bq, gqh, bk, gkh, ctx, gqc, gkc, scal);
  k_prepass<<<MROWS / 4, 256, 0, stream>>>(hs, u2, scal, hsb, gq, gk);

  // Qhat / Khat projections with gating epilogue (M=16384, N=1024, K=1024)
  k_gemm<0><<<dim3(64, 4, 1), 512, 0, stream>>>(hsb, wqb, 1024, 1024, 1024, 0, 0,
      gq, bq, ctxq, qhat, nullptr, 0, 1.f);
  k_gemm<0><<<dim3(64, 4, 1), 512, 0, stream>>>(hsb, wkb, 1024, 1024, 1024, 0, 0,
      gk, bk, ctxk, khat, nullptr, 0, 1.f);

  // V = hs@Wv^T + bv, stored transposed
  k_gemm<2><<<dim3(64, 4, 1), 512, 0, stream>>>(hsb, wvb, 1024, 1024, 1024, 0, 0,
      nullptr, bv, nullptr, vt, nullptr, 0, 1.f);

  // scores = Qhat @ Khat^T * scale (per batch M=N=2048, K=1024), f32 to d_out
  k_gemm<3><<<dim3(8, 8, 8), 512, 0, stream>>>(qhat, khat, 1024, 1024, 1024,
      (long long)S * H, (long long)S * H, nullptr, nullptr, nullptr,
      nullptr, out_scores, (long long)S * S, 0.03125f);

  // softmax -> probs bf16
  k_softmax<<<MROWS, 256, 0, stream>>>(out_scores, probs);

  // output = probs @ V (per batch M=2048, N=1024, K=2048; B operand = Vt)
  k_gemm<4><<<dim3(8, 4, 8), 512, 0, stream>>>(probs, vt, 2048, 2048, 2048,
      (long long)S * S, (long long)H * S, nullptr, nullptr, nullptr,
      nullptr, out_attn, (long long)S * H, 1.f);
}

// Round 9
// 362.842 us; speedup vs baseline: 1.0295x; 1.0190x over previous
//
#include <hip/hip_runtime.h>
#include <cstdint>
#include <cstddef>

#define H 1024
#define NB 8
#define S 2048
#define MROWS (NB*S)

using short8  = __attribute__((ext_vector_type(8))) short;
using ushort8 = __attribute__((ext_vector_type(8))) unsigned short;
using f32x4   = __attribute__((ext_vector_type(4))) float;

__device__ __forceinline__ unsigned short f2bf(float f){
  union { float f; unsigned int u; } c; c.f = f;
  unsigned int u = c.u;
  return (unsigned short)((u + 0x7fffu + ((u >> 16) & 1u)) >> 16);
}

// ---------------- small prep kernels ----------------

// Wq/Wk/Wv f32 -> bf16 (one dispatch)
__global__ void k_cvt3(const float* __restrict__ a, const float* __restrict__ b, const float* __restrict__ c,
                       unsigned short* __restrict__ oa, unsigned short* __restrict__ ob, unsigned short* __restrict__ oc){
  const float* src = blockIdx.y == 0 ? a : (blockIdx.y == 1 ? b : c);
  unsigned short* dst = blockIdx.y == 0 ? oa : (blockIdx.y == 1 ? ob : oc);
  int i = (blockIdx.x * 256 + threadIdx.x) * 4;
  float4 v = *reinterpret_cast<const float4*>(src + i);
  ushort4 o;
  o.x = f2bf(v.x); o.y = f2bf(v.y); o.z = f2bf(v.z); o.w = f2bf(v.w);
  *reinterpret_cast<ushort4*>(dst + i) = o;
}

// u[z][in] = sum_o W_z[o,in]*g_z[o]; partials [z][chunk8][1024]
__global__ void k_colproj(const float* __restrict__ Wq_, const float* __restrict__ Wk_,
                          const float* __restrict__ gqh, const float* __restrict__ gkh,
                          float* __restrict__ up){
  const int z = blockIdx.z;
  const float* W = z ? Wk_ : Wq_;
  const float* g = z ? gkh : gqh;
  const int in = blockIdx.x * 256 + threadIdx.x;
  const int o0 = blockIdx.y * 128;
  float s = 0.f;
  for (int o = 0; o < 128; ++o) s = fmaf(W[(size_t)(o0 + o) * H + in], g[o0 + o], s);
  up[(z * 8 + blockIdx.y) * 1024 + in] = s;
}

__global__ void k_ucombine(const float* __restrict__ up, float* __restrict__ u2){
  int i = blockIdx.x * 256 + threadIdx.x;   // 0..2047
  int z = i >> 10, h = i & 1023;
  float s = 0.f;
  #pragma unroll
  for (int c = 0; c < 8; ++c) s += up[(z * 8 + c) * 1024 + h];
  u2[i] = s;
}

// out[b*H + row] = sum_in Wc[row,in] * ctx[b,in]
__global__ __launch_bounds__(256) void k_ctxproj(const float* __restrict__ Wcq, const float* __restrict__ Wck,
    const float* __restrict__ ctx, float* __restrict__ outq, float* __restrict__ outk){
  __shared__ float cs[NB * H];
  const float* W = blockIdx.y ? Wck : Wcq;
  float* out = blockIdx.y ? outk : outq;
  const int t = threadIdx.x;
  for (int i = t; i < NB * H; i += 256) cs[i] = ctx[i];
  __syncthreads();
  const int wid = t >> 6, lane = t & 63;
  const int row = blockIdx.x * 4 + wid;
  float a[NB];
  #pragma unroll
  for (int b = 0; b < NB; ++b) a[b] = 0.f;
  for (int i0 = 0; i0 < H; i0 += 64){
    const float w = W[(size_t)row * H + i0 + lane];
    #pragma unroll
    for (int b = 0; b < NB; ++b) a[b] = fmaf(w, cs[b * H + i0 + lane], a[b]);
  }
  #pragma unroll
  for (int b = 0; b < NB; ++b){
    float v = a[b];
    #pragma unroll
    for (int off = 32; off > 0; off >>= 1) v += __shfl_xor(v, off);
    if (lane == 0) out[b * H + row] = v;
  }
}

// 18 scalar dots: [0]=bq.gqh [1]=bk.gkh [2+b]=ctx_b.gqc [10+b]=ctx_b.gkc
__global__ __launch_bounds__(512) void k_scalars(const float* __restrict__ bq, const float* __restrict__ gqh,
    const float* __restrict__ bk, const float* __restrict__ gkh,
    const float* __restrict__ ctx, const float* __restrict__ gqc, const float* __restrict__ gkc,
    float* __restrict__ scal){
  const int wid = threadIdx.x >> 6, lane = threadIdx.x & 63;
  for (int d = wid; d < 18; d += 8){
    const float *pa, *pb;
    if (d == 0){ pa = bq; pb = gqh; }
    else if (d == 1){ pa = bk; pb = gkh; }
    else if (d < 10){ pa = ctx + (d - 2) * H; pb = gqc; }
    else { pa = ctx + (d - 10) * H; pb = gkc; }
    float s = 0.f;
    for (int i = lane; i < H; i += 64) s = fmaf(pa[i], pb[i], s);
    #pragma unroll
    for (int off = 32; off > 0; off >>= 1) s += __shfl_xor(s, off);
    if (lane == 0) scal[d] = s;
  }
}

// hs f32 -> bf16, fp32-exact gates per row
__global__ __launch_bounds__(256) void k_prepass(const float* __restrict__ hs,
    const float* __restrict__ u2, const float* __restrict__ scal,
    unsigned short* __restrict__ hsb, float* __restrict__ gq, float* __restrict__ gk){
  const int t = threadIdx.x, wid = t >> 6, lane = t & 63;
  const int row = blockIdx.x * 4 + wid;
  const float* hrow = hs + (size_t)row * H;
  const float* u_q = u2;
  const float* u_k = u2 + 1024;
  unsigned short* orow = hsb + (size_t)row * H;
  float sq = 0.f, sk = 0.f;
  #pragma unroll
  for (int c = 0; c < 4; ++c){
    const int idx = (lane + c * 64) * 4;
    float4 v  = *reinterpret_cast<const float4*>(hrow + idx);
    float4 uq = *reinterpret_cast<const float4*>(u_q + idx);
    float4 uk = *reinterpret_cast<const float4*>(u_k + idx);
    ushort4 o; o.x = f2bf(v.x); o.y = f2bf(v.y); o.z = f2bf(v.z); o.w = f2bf(v.w);
    *reinterpret_cast<ushort4*>(orow + idx) = o;
    sq += v.x*uq.x + v.y*uq.y + v.z*uq.z + v.w*uq.w;
    sk += v.x*uk.x + v.y*uk.y + v.z*uk.z + v.w*uk.w;
  }
  #pragma unroll
  for (int off = 32; off > 0; off >>= 1){
    sq += __shfl_xor(sq, off);
    sk += __shfl_xor(sk, off);
  }
  if (lane == 0){
    const int b = row >> 11;
    gq[row] = 1.f / (1.f + __expf(-(sq + scal[0] + scal[2 + b])));
    gk[row] = 1.f / (1.f + __expf(-(sk + scal[1] + scal[10 + b])));
  }
}

// ---------------- 256x256 8-phase GEMM (bt form: C[i,j] = sum_k A[i,k]*B[j,k]) ----------------
// K-loop: R2's verified single-barrier-per-phase schedule (357 us) — the 2-barrier
// template skeleton measured +10-13 us at these shapes (R8 vs R2; m141-style pinning cost).
// MODE 0: gated bf16 out (Qhat/Khat projections; gate, bias, ctxv used)
// MODE 2: V = hs@Wv^T+bv, store transposed -> bf16 Vt[b][h][s]
// MODE 3: scores = A@B^T * scale -> f32 d_out
// MODE 4: plain f32 out (PV)

#define STG(bufi, opi, halfi, koff, P0, P1) \
  do { __builtin_amdgcn_global_load_lds((const __attribute__((address_space(1))) void*)(P0 + (koff)), \
      (__attribute__((address_space(3))) void*)((char*)(&lds[bufi][opi][halfi][0]) + (wid*2+0)*1024), 16, 0, 0); \
    __builtin_amdgcn_global_load_lds((const __attribute__((address_space(1))) void*)(P1 + (koff)), \
      (__attribute__((address_space(3))) void*)((char*)(&lds[bufi][opi][halfi][0]) + (wid*2+1)*1024), 16, 0, 0); } while(0)
#define STG_A(bufi, halfi, koff) STG(bufi, 0, halfi, koff, sA0, sA1)
#define STG_B(bufi, halfi, koff) STG(bufi, 1, halfi, koff, sB0, sB1)

#define DS_A(bufi, ks, mh) \
  do { _Pragma("unroll") for (int m_ = 0; m_ < 4; ++m_){ \
      const int ar_ = wr*128 + ((mh)*4 + m_)*16 + (lane & 15); \
      const int sl_ = (lane >> 4) ^ ((ar_ >> 1) & 3); \
      af[m_] = *reinterpret_cast<const short8*>(&lds[bufi][0][ks][ar_*32 + sl_*8]); } } while(0)
#define DS_B(bufi, ks) \
  do { _Pragma("unroll") for (int n_ = 0; n_ < 4; ++n_){ \
      const int br_ = wc*64 + n_*16 + (lane & 15); \
      const int sl_ = (lane >> 4) ^ ((br_ >> 1) & 3); \
      bf[n_] = *reinterpret_cast<const short8*>(&lds[bufi][1][ks][br_*32 + sl_*8]); } } while(0)
#define MFMA16(mh) \
  do { __builtin_amdgcn_s_setprio(1); \
    _Pragma("unroll") for (int m_ = 0; m_ < 4; ++m_) \
      _Pragma("unroll") for (int n_ = 0; n_ < 4; ++n_) \
        acc[(mh)*4 + m_][n_] = __builtin_amdgcn_mfma_f32_16x16x32_bf16(af[m_], bf[n_], acc[(mh)*4 + m_][n_], 0, 0, 0); \
    __builtin_amdgcn_s_setprio(0); } while(0)
#define VM4() do { asm volatile("s_waitcnt vmcnt(4)" ::: "memory"); } while(0)
#define VM0() do { asm volatile("s_waitcnt vmcnt(0)" ::: "memory"); } while(0)
#define BAR() do { asm volatile("" ::: "memory"); __builtin_amdgcn_s_barrier(); asm volatile("" ::: "memory"); } while(0)

template<int MODE>
__global__ __launch_bounds__(512, 2)
void k_gemm(const unsigned short* __restrict__ A, const unsigned short* __restrict__ B,
            int K, int ldA, int ldB, long long Abatch, long long Bbatch,
            const float* __restrict__ gate, const float* __restrict__ bias,
            const float* __restrict__ ctxv,
            unsigned short* __restrict__ outb, float* __restrict__ outf,
            long long outBatch, float scale)
{
  // [buf][op A=0,B=1][khalf][256 rows * 4 slots * 8 bf16] = 128 KiB total
  __shared__ __align__(16) short lds[2][2][2][8192];

  const int t = threadIdx.x;
  const int wid = t >> 6, lane = t & 63;
  const int wr = wid >> 2, wc = wid & 3;      // 2 x 4 wave grid
  const int bz = blockIdx.z;
  const unsigned short* Ab = A + (size_t)bz * (size_t)Abatch;
  const unsigned short* Bb = B + (size_t)bz * (size_t)Bbatch;
  const int row0 = blockIdx.x * 256;
  const int col0 = blockIdx.y * 256;

  // staging constants: thread's 2 chunks within a 16KB half (256 rows x 4 slots of 16B)
  const int c0 = (wid*2 + 0)*64 + lane;
  const int c1 = (wid*2 + 1)*64 + lane;
  const int r0s = c0 >> 2, r1s = c1 >> 2;
  const int kc0 = (c0 & 3) ^ ((r0s >> 1) & 3);   // pre-swizzled global k-chunk (involution)
  const int kc1 = (c1 & 3) ^ ((r1s >> 1) & 3);
  const unsigned short* sA0 = Ab + (size_t)(row0 + r0s) * (size_t)ldA + kc0*8;
  const unsigned short* sA1 = Ab + (size_t)(row0 + r1s) * (size_t)ldA + kc1*8;
  const unsigned short* sB0 = Bb + (size_t)(col0 + r0s) * (size_t)ldB + kc0*8;
  const unsigned short* sB1 = Bb + (size_t)(col0 + r1s) * (size_t)ldB + kc1*8;

  f32x4 acc[8][4] = {};
  short8 af[4], bf[4];

  // prologue: stage tile 0 into buf0 (4 halves), drain, barrier
  STG_A(0, 0, 0); STG_B(0, 0, 0); STG_A(0, 1, 32); STG_B(0, 1, 32);
  VM0(); BAR();

  const int niter = K >> 7;       // 2 K-tiles (of 64) per iteration
  for (int it = 0; it < niter; ++it){
    const int t1k = (it*2 + 1) << 6;
    const int t2k = (it*2 + 2) << 6;
    const bool more = (it + 1 < niter);
    // R2 schedule: {DS || STG ; MFMA ; [vmcnt] ; BAR} — one barrier per phase
    DS_A(0, 0, 0); DS_B(0, 0); STG_A(1, 0, t1k);      MFMA16(0);                              BAR();
    DS_A(0, 0, 1);             STG_B(1, 0, t1k);      MFMA16(1); VM4();                       BAR();
    DS_A(0, 1, 0); DS_B(0, 1); STG_A(1, 1, t1k + 32); MFMA16(0);                              BAR();
    DS_A(0, 1, 1);             STG_B(1, 1, t1k + 32); MFMA16(1); if (more) { VM4(); } else { VM0(); } BAR();
    DS_A(1, 0, 0); DS_B(1, 0); if (more) { STG_A(0, 0, t2k); }      MFMA16(0);                BAR();
    DS_A(1, 0, 1);             if (more) { STG_B(0, 0, t2k); }      MFMA16(1); if (more) { VM4(); } BAR();
    DS_A(1, 1, 0); DS_B(1, 1); if (more) { STG_A(0, 1, t2k + 32); } MFMA16(0);                BAR();
    DS_A(1, 1, 1);             if (more) { STG_B(0, 1, t2k + 32); } MFMA16(1); if (more) { VM4(); } BAR();
  }

  // ---- epilogues ---- (C/D layout m89: col=lane&15, row=(lane>>4)*4+reg)
  if constexpr (MODE == 0){
    // gated projection: out = (1-g)*(acc+bias) + g*ctx, LDS-bounce -> 16B stores
    unsigned short* tp = (unsigned short*)lds;          // [128][264] = 67584 B
    float* gl = (float*)((char*)lds + 69632);           // gate rows [256]
    float* bl = gl + 256;                                // bias cols [256]
    float* cl = bl + 256;                                // ctx  cols [256]
    const int b = row0 >> 11;
    __syncthreads();
    if (t < 256){
      gl[t] = gate[row0 + t];
      bl[t] = bias[col0 + t];
      cl[t] = ctxv[b * H + col0 + t];
    }
    __syncthreads();
    #pragma unroll
    for (int ci = 0; ci < 2; ++ci){
      if (ci) __syncthreads();
      if (wr == ci){
        #pragma unroll
        for (int mi = 0; mi < 8; ++mi)
          #pragma unroll
          for (int r = 0; r < 4; ++r){
            const int lr = mi*16 + (lane >> 4)*4 + r;
            const float g = gl[ci*128 + lr];
            #pragma unroll
            for (int n = 0; n < 4; ++n){
              const int lc = wc*64 + n*16 + (lane & 15);
              const float q = acc[mi][n][r] + bl[lc];
              tp[lr*264 + lc] = f2bf((1.f - g) * q + g * cl[lc]);
            }
          }
      }
      __syncthreads();
      const int rr = t & 127;
      const int cc = (t >> 7) * 64;
      const unsigned short* srcp = tp + rr*264 + cc;
      unsigned short* dst = outb + (size_t)(row0 + ci*128 + rr) * H + col0 + cc;
      #pragma unroll
      for (int i = 0; i < 64; i += 8)
        *reinterpret_cast<ushort8*>(dst + i) = *reinterpret_cast<const ushort8*>(srcp + i);
    }
  } else if constexpr (MODE == 2){
    // transposed store: write [h][s] LDS quadrants, then 64B-contiguous global stores
    unsigned short* tp = (unsigned short*)lds;   // [128 h][136 s]
    const int bb = row0 >> 11;
    const int s0 = row0 & (S - 1);
    #pragma unroll
    for (int ci = 0; ci < 2; ++ci)
      #pragma unroll
      for (int cj = 0; cj < 2; ++cj){
        __syncthreads();
        if (wr == ci && (wc >> 1) == cj){
          const int lc0 = (wc & 1) * 64;
          #pragma unroll
          for (int mi = 0; mi < 8; ++mi)
            #pragma unroll
            for (int n = 0; n < 4; ++n)
              #pragma unroll
              for (int r = 0; r < 4; ++r){
                const int lr = mi*16 + (lane >> 4)*4 + r;           // s
                const int lc = lc0 + n*16 + (lane & 15);            // h
                tp[lc*136 + lr] = f2bf(acc[mi][n][r] + bias[col0 + cj*128 + lc]);
              }
        }
        __syncthreads();
        const int hh = t & 127;
        const int sc = (t >> 7) * 32;
        const unsigned short* srcp = tp + hh*136 + sc;
        unsigned short* vout = outb + (size_t)bb * H * S + (size_t)(col0 + cj*128 + hh) * S
                                    + (size_t)(s0 + ci*128 + sc);
        #pragma unroll
        for (int i2 = 0; i2 < 32; i2 += 8)
          *reinterpret_cast<ushort8*>(vout + i2) = *reinterpret_cast<const ushort8*>(srcp + i2);
      }
  } else if constexpr (MODE == 3){
    #pragma unroll
    for (int mi = 0; mi < 8; ++mi)
      #pragma unroll
      for (int n = 0; n < 4; ++n)
        #pragma unroll
        for (int r = 0; r < 4; ++r){
          const int grow = row0 + wr*128 + mi*16 + (lane >> 4)*4 + r;
          const int gcol = col0 + wc*64 + n*16 + (lane & 15);
          outf[(size_t)bz * (size_t)outBatch + (size_t)grow * S + gcol] = acc[mi][n][r] * scale;
        }
  } else {
    #pragma unroll
    for (int mi = 0; mi < 8; ++mi)
      #pragma unroll
      for (int n = 0; n < 4; ++n)
        #pragma unroll
        for (int r = 0; r < 4; ++r){
          const int grow = row0 + wr*128 + mi*16 + (lane >> 4)*4 + r;
          const int gcol = col0 + wc*64 + n*16 + (lane & 15);
          outf[(size_t)bz * (size_t)outBatch + (size_t)grow * H + gcol] = acc[mi][n][r];
        }
  }
}

// ---------------- softmax ----------------
__global__ __launch_bounds__(256) void k_softmax(const float* __restrict__ scores,
                                                 unsigned short* __restrict__ probs){
  const int row = blockIdx.x;
  const float* srow = scores + (size_t)row * S;
  unsigned short* prow = probs + (size_t)row * S;
  const int t = threadIdx.x, wid = t >> 6, lane = t & 63;
  __shared__ float red[8];
  float4 v0 = *reinterpret_cast<const float4*>(srow + t * 4);
  float4 v1 = *reinterpret_cast<const float4*>(srow + 1024 + t * 4);
  float m = fmaxf(fmaxf(fmaxf(v0.x, v0.y), fmaxf(v0.z, v0.w)),
                  fmaxf(fmaxf(v1.x, v1.y), fmaxf(v1.z, v1.w)));
  #pragma unroll
  for (int off = 32; off > 0; off >>= 1) m = fmaxf(m, __shfl_xor(m, off));
  if (lane == 0) red[wid] = m;
  __syncthreads();
  m = fmaxf(fmaxf(red[0], red[1]), fmaxf(red[2], red[3]));
  float4 e0, e1;
  e0.x = __expf(v0.x - m); e0.y = __expf(v0.y - m); e0.z = __expf(v0.z - m); e0.w = __expf(v0.w - m);
  e1.x = __expf(v1.x - m); e1.y = __expf(v1.y - m); e1.z = __expf(v1.z - m); e1.w = __expf(v1.w - m);
  float s = (e0.x + e0.y + e0.z + e0.w) + (e1.x + e1.y + e1.z + e1.w);
  #pragma unroll
  for (int off = 32; off > 0; off >>= 1) s += __shfl_xor(s, off);
  if (lane == 0) red[4 + wid] = s;
  __syncthreads();
  s = (red[4] + red[5]) + (red[6] + red[7]);
  const float inv = 1.f / s;
  ushort4 o;
  o.x = f2bf(e0.x * inv); o.y = f2bf(e0.y * inv); o.z = f2bf(e0.z * inv); o.w = f2bf(e0.w * inv);
  *reinterpret_cast<ushort4*>(prow + t * 4) = o;
  o.x = f2bf(e1.x * inv); o.y = f2bf(e1.y * inv); o.z = f2bf(e1.z * inv); o.w = f2bf(e1.w * inv);
  *reinterpret_cast<ushort4*>(prow + 1024 + t * 4) = o;
}

// ---------------- launch ----------------
extern "C" void kernel_launch(void* const* d_in, const int* in_sizes, int n_in,
                              void* d_out, int out_size, void* d_ws, size_t ws_size,
                              hipStream_t stream) {
  const float* hs  = (const float*)d_in[0];
  const float* ctx = (const float*)d_in[1];
  const float* Wq  = (const float*)d_in[2];
  const float* bq  = (const float*)d_in[3];
  const float* Wk  = (const float*)d_in[4];
  const float* bk  = (const float*)d_in[5];
  const float* Wv  = (const float*)d_in[6];
  const float* bv  = (const float*)d_in[7];
  const float* Wcq = (const float*)d_in[8];
  const float* Wck = (const float*)d_in[9];
  const float* gqh = (const float*)d_in[10];
  const float* gkh = (const float*)d_in[11];
  const float* gqc = (const float*)d_in[12];
  const float* gkc = (const float*)d_in[13];

  char* ws = (char*)d_ws;    // ~768 MB available
  unsigned short* hsb   = (unsigned short*)(ws);                   // 33.5 MB
  unsigned short* qhat  = (unsigned short*)(ws + 33554432);        // 33.5 MB
  unsigned short* khat  = (unsigned short*)(ws + 67108864);        // 33.5 MB
  unsigned short* vt    = (unsigned short*)(ws + 100663296);       // 33.5 MB
  unsigned short* probs = (unsigned short*)(ws + 134217728);       // 33.5 MB
  unsigned short* wqb   = (unsigned short*)(ws + 167772160);       // 2 MB
  unsigned short* wkb   = (unsigned short*)(ws + 169869312);       // 2 MB
  unsigned short* wvb   = (unsigned short*)(ws + 171966464);       // 2 MB
  float* up    = (float*)(ws + 174063616);                         // 64 KB
  float* u2    = (float*)(ws + 174129152);                         // 8 KB
  float* ctxq  = (float*)(ws + 174137344);                         // 32 KB
  float* ctxk  = (float*)(ws + 174170112);                         // 32 KB
  float* gq    = (float*)(ws + 174202880);                         // 64 KB
  float* gk    = (float*)(ws + 174268416);                         // 64 KB
  float* scal  = (float*)(ws + 174333952);                         // 256 B

  float* out_attn   = (float*)d_out;                        // [NB,S,H]
  float* out_scores = out_attn + (size_t)MROWS * H;         // [NB,S,S]

  // prep (6 dispatches)
  k_cvt3<<<dim3(1024, 3), 256, 0, stream>>>(Wq, Wk, Wv, wqb, wkb, wvb);
  k_colproj<<<dim3(4, 8, 2), 256, 0, stream>>>(Wq, Wk, gqh, gkh, up);
  k_ucombine<<<8, 256, 0, stream>>>(up, u2);
  k_ctxproj<<<dim3(256, 2), 256, 0, stream>>>(Wcq, Wck, ctx, ctxq, ctxk);
  k_scalars<<<1, 512, 0, stream>>>(bq, gqh, bk, gkh, ctx, gqc, gkc, scal);
  k_prepass<<<MROWS / 4, 256, 0, stream>>>(hs, u2, scal, hsb, gq, gk);

  // Qhat / Khat projections with gating epilogue (M=16384, N=1024, K=1024)
  k_gemm<0><<<dim3(64, 4, 1), 512, 0, stream>>>(hsb, wqb, 1024, 1024, 1024, 0, 0,
      gq, bq, ctxq, qhat, nullptr, 0, 1.f);
  k_gemm<0><<<dim3(64, 4, 1), 512, 0, stream>>>(hsb, wkb, 1024, 1024, 1024, 0, 0,
      gk, bk, ctxk, khat, nullptr, 0, 1.f);

  // V = hs@Wv^T + bv, stored transposed
  k_gemm<2><<<dim3(64, 4, 1), 512, 0, stream>>>(hsb, wvb, 1024, 1024, 1024, 0, 0,
      nullptr, bv, nullptr, vt, nullptr, 0, 1.f);

  // scores = Qhat @ Khat^T * scale (per batch M=N=2048, K=1024), f32 to d_out
  k_gemm<3><<<dim3(8, 8, 8), 512, 0, stream>>>(qhat, khat, 1024, 1024, 1024,
      (long long)S * H, (long long)S * H, nullptr, nullptr, nullptr,
      nullptr, out_scores, (long long)S * S, 0.03125f);

  // softmax -> probs bf16
  k_softmax<<<MROWS, 256, 0, stream>>>(out_scores, probs);

  // output = probs @ V (per batch M=2048, N=1024, K=2048; B operand = Vt)
  k_gemm<4><<<dim3(8, 4, 8), 512, 0, stream>>>(probs, vt, 2048, 2048, 2048,
      (long long)S * S, (long long)H * S, nullptr, nullptr, nullptr,
      nullptr, out_attn, (long long)S * H, 1.f);
}

// Round 10
// 338.824 us; speedup vs baseline: 1.1025x; 1.0709x over previous
//
#include <hip/hip_runtime.h>
#include <cstdint>
#include <cstddef>

#define H 1024
#define NB 8
#define S 2048
#define MROWS (NB*S)

using short8  = __attribute__((ext_vector_type(8))) short;
using ushort8 = __attribute__((ext_vector_type(8))) unsigned short;
using f32x4   = __attribute__((ext_vector_type(4))) float;

__device__ __forceinline__ unsigned short f2bf(float f){
  union { float f; unsigned int u; } c; c.f = f;
  unsigned int u = c.u;
  return (unsigned short)((u + 0x7fffu + ((u >> 16) & 1u)) >> 16);
}

// ---------------- merged prep kernel ----------------
// blocks [0,3072): W cvt f32->bf16 ; [3072,3136): colproj partials ;
// [3136,3648): ctxproj ; 3648: scalar dots
__global__ __launch_bounds__(256) void k_prep(
    const float* __restrict__ Wq, const float* __restrict__ Wk, const float* __restrict__ Wv,
    const float* __restrict__ Wcq, const float* __restrict__ Wck, const float* __restrict__ ctx,
    const float* __restrict__ gqh, const float* __restrict__ gkh,
    const float* __restrict__ bq, const float* __restrict__ bk,
    const float* __restrict__ gqc, const float* __restrict__ gkc,
    unsigned short* __restrict__ wqb, unsigned short* __restrict__ wkb, unsigned short* __restrict__ wvb,
    float* __restrict__ up, float* __restrict__ ctxq, float* __restrict__ ctxk,
    float* __restrict__ scal)
{
  __shared__ float cs[NB * H];
  const int bid = blockIdx.x;
  const int t = threadIdx.x;
  if (bid < 3072){
    const int y = bid >> 10;
    const int x = bid & 1023;
    const float* src = y == 0 ? Wq : (y == 1 ? Wk : Wv);
    unsigned short* dst = y == 0 ? wqb : (y == 1 ? wkb : wvb);
    const int i = (x * 256 + t) * 4;
    float4 v = *reinterpret_cast<const float4*>(src + i);
    ushort4 o; o.x = f2bf(v.x); o.y = f2bf(v.y); o.z = f2bf(v.z); o.w = f2bf(v.w);
    *reinterpret_cast<ushort4*>(dst + i) = o;
  } else if (bid < 3136){
    const int sub = bid - 3072;
    const int z = sub >> 5;          // 0..1
    const int y = (sub >> 2) & 7;    // 0..7
    const int x = sub & 3;           // 0..3
    const float* W = z ? Wk : Wq;
    const float* g = z ? gkh : gqh;
    const int in = x * 256 + t;
    const int o0 = y * 128;
    float s = 0.f;
    for (int o = 0; o < 128; ++o) s = fmaf(W[(size_t)(o0 + o) * H + in], g[o0 + o], s);
    up[(z * 8 + y) * 1024 + in] = s;
  } else if (bid < 3648){
    const int sub = bid - 3136;
    const int y = sub >> 8;          // 0..1
    const int x = sub & 255;
    const float* W = y ? Wck : Wcq;
    float* out = y ? ctxk : ctxq;
    for (int i = t; i < NB * H; i += 256) cs[i] = ctx[i];
    __syncthreads();
    const int wid = t >> 6, lane = t & 63;
    const int row = x * 4 + wid;
    float a[NB];
    #pragma unroll
    for (int b = 0; b < NB; ++b) a[b] = 0.f;
    for (int i0 = 0; i0 < H; i0 += 64){
      const float w = W[(size_t)row * H + i0 + lane];
      #pragma unroll
      for (int b = 0; b < NB; ++b) a[b] = fmaf(w, cs[b * H + i0 + lane], a[b]);
    }
    #pragma unroll
    for (int b = 0; b < NB; ++b){
      float v = a[b];
      #pragma unroll
      for (int off = 32; off > 0; off >>= 1) v += __shfl_xor(v, off);
      if (lane == 0) out[b * H + row] = v;
    }
  } else {
    // 18 scalar dots, 4 waves
    const int wid = t >> 6, lane = t & 63;
    for (int d = wid; d < 18; d += 4){
      const float *pa, *pb;
      if (d == 0){ pa = bq; pb = gqh; }
      else if (d == 1){ pa = bk; pb = gkh; }
      else if (d < 10){ pa = ctx + (d - 2) * H; pb = gqc; }
      else { pa = ctx + (d - 10) * H; pb = gkc; }
      float s = 0.f;
      for (int i = lane; i < H; i += 64) s = fmaf(pa[i], pb[i], s);
      #pragma unroll
      for (int off = 32; off > 0; off >>= 1) s += __shfl_xor(s, off);
      if (lane == 0) scal[d] = s;
    }
  }
}

__global__ void k_ucombine(const float* __restrict__ up, float* __restrict__ u2){
  int i = blockIdx.x * 256 + threadIdx.x;   // 0..2047
  int z = i >> 10, h = i & 1023;
  float s = 0.f;
  #pragma unroll
  for (int c = 0; c < 8; ++c) s += up[(z * 8 + c) * 1024 + h];
  u2[i] = s;
}

// hs f32 -> bf16, fp32-exact gates per row
__global__ __launch_bounds__(256) void k_prepass(const float* __restrict__ hs,
    const float* __restrict__ u2, const float* __restrict__ scal,
    unsigned short* __restrict__ hsb, float* __restrict__ gq, float* __restrict__ gk){
  const int t = threadIdx.x, wid = t >> 6, lane = t & 63;
  const int row = blockIdx.x * 4 + wid;
  const float* hrow = hs + (size_t)row * H;
  const float* u_q = u2;
  const float* u_k = u2 + 1024;
  unsigned short* orow = hsb + (size_t)row * H;
  float sq = 0.f, sk = 0.f;
  #pragma unroll
  for (int c = 0; c < 4; ++c){
    const int idx = (lane + c * 64) * 4;
    float4 v  = *reinterpret_cast<const float4*>(hrow + idx);
    float4 uq = *reinterpret_cast<const float4*>(u_q + idx);
    float4 uk = *reinterpret_cast<const float4*>(u_k + idx);
    ushort4 o; o.x = f2bf(v.x); o.y = f2bf(v.y); o.z = f2bf(v.z); o.w = f2bf(v.w);
    *reinterpret_cast<ushort4*>(orow + idx) = o;
    sq += v.x*uq.x + v.y*uq.y + v.z*uq.z + v.w*uq.w;
    sk += v.x*uk.x + v.y*uk.y + v.z*uk.z + v.w*uk.w;
  }
  #pragma unroll
  for (int off = 32; off > 0; off >>= 1){
    sq += __shfl_xor(sq, off);
    sk += __shfl_xor(sk, off);
  }
  if (lane == 0){
    const int b = row >> 11;
    gq[row] = 1.f / (1.f + __expf(-(sq + scal[0] + scal[2 + b])));
    gk[row] = 1.f / (1.f + __expf(-(sk + scal[1] + scal[10 + b])));
  }
}

// ---------------- 256x256 GEMM (bt form), R2 single-barrier schedule ----------------
// MODE 0: merged QKV. B spans [wqb|wkb|wvb] (N=3072). Per 1024-col group:
//         group 0/1 -> gated bf16 out (qhat/khat); group 2 -> V transposed (vt)
// MODE 3: scores = A@B^T * scale -> f32 d_out
// MODE 4: plain f32 out (PV)

#define STG(bufi, opi, halfi, koff, P0, P1) \
  do { __builtin_amdgcn_global_load_lds((const __attribute__((address_space(1))) void*)(P0 + (koff)), \
      (__attribute__((address_space(3))) void*)((char*)(&lds[bufi][opi][halfi][0]) + (wid*2+0)*1024), 16, 0, 0); \
    __builtin_amdgcn_global_load_lds((const __attribute__((address_space(1))) void*)(P1 + (koff)), \
      (__attribute__((address_space(3))) void*)((char*)(&lds[bufi][opi][halfi][0]) + (wid*2+1)*1024), 16, 0, 0); } while(0)
#define STG_A(bufi, halfi, koff) STG(bufi, 0, halfi, koff, sA0, sA1)
#define STG_B(bufi, halfi, koff) STG(bufi, 1, halfi, koff, sB0, sB1)

#define DS_A(bufi, ks, mh) \
  do { _Pragma("unroll") for (int m_ = 0; m_ < 4; ++m_){ \
      const int ar_ = wr*128 + ((mh)*4 + m_)*16 + (lane & 15); \
      const int sl_ = (lane >> 4) ^ ((ar_ >> 1) & 3); \
      af[m_] = *reinterpret_cast<const short8*>(&lds[bufi][0][ks][ar_*32 + sl_*8]); } } while(0)
#define DS_B(bufi, ks) \
  do { _Pragma("unroll") for (int n_ = 0; n_ < 4; ++n_){ \
      const int br_ = wc*64 + n_*16 + (lane & 15); \
      const int sl_ = (lane >> 4) ^ ((br_ >> 1) & 3); \
      bf[n_] = *reinterpret_cast<const short8*>(&lds[bufi][1][ks][br_*32 + sl_*8]); } } while(0)
#define MFMA16(mh) \
  do { __builtin_amdgcn_s_setprio(1); \
    _Pragma("unroll") for (int m_ = 0; m_ < 4; ++m_) \
      _Pragma("unroll") for (int n_ = 0; n_ < 4; ++n_) \
        acc[(mh)*4 + m_][n_] = __builtin_amdgcn_mfma_f32_16x16x32_bf16(af[m_], bf[n_], acc[(mh)*4 + m_][n_], 0, 0, 0); \
    __builtin_amdgcn_s_setprio(0); } while(0)
#define VM4() do { asm volatile("s_waitcnt vmcnt(4)" ::: "memory"); } while(0)
#define VM0() do { asm volatile("s_waitcnt vmcnt(0)" ::: "memory"); } while(0)
#define BAR() do { asm volatile("" ::: "memory"); __builtin_amdgcn_s_barrier(); asm volatile("" ::: "memory"); } while(0)

template<int MODE>
__global__ __launch_bounds__(512, 2)
void k_gemm(const unsigned short* __restrict__ A, const unsigned short* __restrict__ B,
            int K, int ldA, int ldB, long long Abatch, long long Bbatch,
            const float* __restrict__ gq, const float* __restrict__ gk,
            const float* __restrict__ bq, const float* __restrict__ bk, const float* __restrict__ bv,
            const float* __restrict__ cq, const float* __restrict__ ck,
            unsigned short* __restrict__ oq, unsigned short* __restrict__ ok, unsigned short* __restrict__ ov,
            float* __restrict__ outf, long long outBatch, float scale)
{
  // [buf][op A=0,B=1][khalf][256 rows * 4 slots * 8 bf16] = 128 KiB total
  __shared__ __align__(16) short lds[2][2][2][8192];

  const int t = threadIdx.x;
  const int wid = t >> 6, lane = t & 63;
  const int wr = wid >> 2, wc = wid & 3;      // 2 x 4 wave grid
  const int bz = blockIdx.z;
  const unsigned short* Ab = A + (size_t)bz * (size_t)Abatch;
  const unsigned short* Bb = B + (size_t)bz * (size_t)Bbatch;
  const int row0 = blockIdx.x * 256;
  const int col0 = blockIdx.y * 256;

  const int c0 = (wid*2 + 0)*64 + lane;
  const int c1 = (wid*2 + 1)*64 + lane;
  const int r0s = c0 >> 2, r1s = c1 >> 2;
  const int kc0 = (c0 & 3) ^ ((r0s >> 1) & 3);   // pre-swizzled global k-chunk (involution)
  const int kc1 = (c1 & 3) ^ ((r1s >> 1) & 3);
  const unsigned short* sA0 = Ab + (size_t)(row0 + r0s) * (size_t)ldA + kc0*8;
  const unsigned short* sA1 = Ab + (size_t)(row0 + r1s) * (size_t)ldA + kc1*8;
  const unsigned short* sB0 = Bb + (size_t)(col0 + r0s) * (size_t)ldB + kc0*8;
  const unsigned short* sB1 = Bb + (size_t)(col0 + r1s) * (size_t)ldB + kc1*8;

  f32x4 acc[8][4] = {};
  short8 af[4], bf[4];

  STG_A(0, 0, 0); STG_B(0, 0, 0); STG_A(0, 1, 32); STG_B(0, 1, 32);
  VM0(); BAR();

  const int niter = K >> 7;       // 2 K-tiles (of 64) per iteration
  for (int it = 0; it < niter; ++it){
    const int t1k = (it*2 + 1) << 6;
    const int t2k = (it*2 + 2) << 6;
    const bool more = (it + 1 < niter);
    // R2 schedule: {DS || STG ; MFMA ; [vmcnt] ; BAR} — one barrier per phase
    DS_A(0, 0, 0); DS_B(0, 0); STG_A(1, 0, t1k);      MFMA16(0);                              BAR();
    DS_A(0, 0, 1);             STG_B(1, 0, t1k);      MFMA16(1); VM4();                       BAR();
    DS_A(0, 1, 0); DS_B(0, 1); STG_A(1, 1, t1k + 32); MFMA16(0);                              BAR();
    DS_A(0, 1, 1);             STG_B(1, 1, t1k + 32); MFMA16(1); if (more) { VM4(); } else { VM0(); } BAR();
    DS_A(1, 0, 0); DS_B(1, 0); if (more) { STG_A(0, 0, t2k); }      MFMA16(0);                BAR();
    DS_A(1, 0, 1);             if (more) { STG_B(0, 0, t2k); }      MFMA16(1); if (more) { VM4(); } BAR();
    DS_A(1, 1, 0); DS_B(1, 1); if (more) { STG_A(0, 1, t2k + 32); } MFMA16(0);                BAR();
    DS_A(1, 1, 1);             if (more) { STG_B(0, 1, t2k + 32); } MFMA16(1); if (more) { VM4(); } BAR();
  }

  // ---- epilogues ---- (C/D layout m89: col=lane&15, row=(lane>>4)*4+reg)
  if constexpr (MODE == 0){
    const int which = col0 >> 10;        // 0=Q 1=K 2=V
    const int lcol  = col0 & 1023;
    if (which < 2){
      const float* gate = which ? gk : gq;
      const float* bias = which ? bk : bq;
      const float* ctxv = which ? ck : cq;
      unsigned short* outb = which ? ok : oq;
      unsigned short* tp = (unsigned short*)lds;          // [128][264]
      float* gl = (float*)((char*)lds + 69632);
      float* bl = gl + 256;
      float* cl = bl + 256;
      const int b = row0 >> 11;
      __syncthreads();
      if (t < 256){
        gl[t] = gate[row0 + t];
        bl[t] = bias[lcol + t];
        cl[t] = ctxv[b * H + lcol + t];
      }
      __syncthreads();
      #pragma unroll
      for (int ci = 0; ci < 2; ++ci){
        if (ci) __syncthreads();
        if (wr == ci){
          #pragma unroll
          for (int mi = 0; mi < 8; ++mi)
            #pragma unroll
            for (int r = 0; r < 4; ++r){
              const int lr = mi*16 + (lane >> 4)*4 + r;
              const float g = gl[ci*128 + lr];
              #pragma unroll
              for (int n = 0; n < 4; ++n){
                const int lc = wc*64 + n*16 + (lane & 15);
                const float q = acc[mi][n][r] + bl[lc];
                tp[lr*264 + lc] = f2bf((1.f - g) * q + g * cl[lc]);
              }
            }
        }
        __syncthreads();
        const int rr = t & 127;
        const int cc = (t >> 7) * 64;
        const unsigned short* srcp = tp + rr*264 + cc;
        unsigned short* dst = outb + (size_t)(row0 + ci*128 + rr) * H + lcol + cc;
        #pragma unroll
        for (int i = 0; i < 64; i += 8)
          *reinterpret_cast<ushort8*>(dst + i) = *reinterpret_cast<const ushort8*>(srcp + i);
      }
    } else {
      // V transposed store path
      unsigned short* tp = (unsigned short*)lds;   // [128 h][136 s]
      const int bb = row0 >> 11;
      const int s0 = row0 & (S - 1);
      #pragma unroll
      for (int ci = 0; ci < 2; ++ci)
        #pragma unroll
        for (int cj = 0; cj < 2; ++cj){
          __syncthreads();
          if (wr == ci && (wc >> 1) == cj){
            const int lc0 = (wc & 1) * 64;
            #pragma unroll
            for (int mi = 0; mi < 8; ++mi)
              #pragma unroll
              for (int n = 0; n < 4; ++n)
                #pragma unroll
                for (int r = 0; r < 4; ++r){
                  const int lr = mi*16 + (lane >> 4)*4 + r;           // s
                  const int lc = lc0 + n*16 + (lane & 15);            // h
                  tp[lc*136 + lr] = f2bf(acc[mi][n][r] + bv[lcol + cj*128 + lc]);
                }
          }
          __syncthreads();
          const int hh = t & 127;
          const int sc = (t >> 7) * 32;
          const unsigned short* srcp = tp + hh*136 + sc;
          unsigned short* vout = ov + (size_t)bb * H * S + (size_t)(lcol + cj*128 + hh) * S
                                    + (size_t)(s0 + ci*128 + sc);
          #pragma unroll
          for (int i2 = 0; i2 < 32; i2 += 8)
            *reinterpret_cast<ushort8*>(vout + i2) = *reinterpret_cast<const ushort8*>(srcp + i2);
        }
    }
  } else if constexpr (MODE == 3){
    #pragma unroll
    for (int mi = 0; mi < 8; ++mi)
      #pragma unroll
      for (int n = 0; n < 4; ++n)
        #pragma unroll
        for (int r = 0; r < 4; ++r){
          const int grow = row0 + wr*128 + mi*16 + (lane >> 4)*4 + r;
          const int gcol = col0 + wc*64 + n*16 + (lane & 15);
          outf[(size_t)bz * (size_t)outBatch + (size_t)grow * S + gcol] = acc[mi][n][r] * scale;
        }
  } else {
    #pragma unroll
    for (int mi = 0; mi < 8; ++mi)
      #pragma unroll
      for (int n = 0; n < 4; ++n)
        #pragma unroll
        for (int r = 0; r < 4; ++r){
          const int grow = row0 + wr*128 + mi*16 + (lane >> 4)*4 + r;
          const int gcol = col0 + wc*64 + n*16 + (lane & 15);
          outf[(size_t)bz * (size_t)outBatch + (size_t)grow * H + gcol] = acc[mi][n][r];
        }
  }
}

// ---------------- softmax ----------------
__global__ __launch_bounds__(256) void k_softmax(const float* __restrict__ scores,
                                                 unsigned short* __restrict__ probs){
  const int row = blockIdx.x;
  const float* srow = scores + (size_t)row * S;
  unsigned short* prow = probs + (size_t)row * S;
  const int t = threadIdx.x, wid = t >> 6, lane = t & 63;
  __shared__ float red[8];
  float4 v0 = *reinterpret_cast<const float4*>(srow + t * 4);
  float4 v1 = *reinterpret_cast<const float4*>(srow + 1024 + t * 4);
  float m = fmaxf(fmaxf(fmaxf(v0.x, v0.y), fmaxf(v0.z, v0.w)),
                  fmaxf(fmaxf(v1.x, v1.y), fmaxf(v1.z, v1.w)));
  #pragma unroll
  for (int off = 32; off > 0; off >>= 1) m = fmaxf(m, __shfl_xor(m, off));
  if (lane == 0) red[wid] = m;
  __syncthreads();
  m = fmaxf(fmaxf(red[0], red[1]), fmaxf(red[2], red[3]));
  float4 e0, e1;
  e0.x = __expf(v0.x - m); e0.y = __expf(v0.y - m); e0.z = __expf(v0.z - m); e0.w = __expf(v0.w - m);
  e1.x = __expf(v1.x - m); e1.y = __expf(v1.y - m); e1.z = __expf(v1.z - m); e1.w = __expf(v1.w - m);
  float s = (e0.x + e0.y + e0.z + e0.w) + (e1.x + e1.y + e1.z + e1.w);
  #pragma unroll
  for (int off = 32; off > 0; off >>= 1) s += __shfl_xor(s, off);
  if (lane == 0) red[4 + wid] = s;
  __syncthreads();
  s = (red[4] + red[5]) + (red[6] + red[7]);
  const float inv = 1.f / s;
  ushort4 o;
  o.x = f2bf(e0.x * inv); o.y = f2bf(e0.y * inv); o.z = f2bf(e0.z * inv); o.w = f2bf(e0.w * inv);
  *reinterpret_cast<ushort4*>(prow + t * 4) = o;
  o.x = f2bf(e1.x * inv); o.y = f2bf(e1.y * inv); o.z = f2bf(e1.z * inv); o.w = f2bf(e1.w * inv);
  *reinterpret_cast<ushort4*>(prow + 1024 + t * 4) = o;
}

// ---------------- launch ----------------
extern "C" void kernel_launch(void* const* d_in, const int* in_sizes, int n_in,
                              void* d_out, int out_size, void* d_ws, size_t ws_size,
                              hipStream_t stream) {
  const float* hs  = (const float*)d_in[0];
  const float* ctx = (const float*)d_in[1];
  const float* Wq  = (const float*)d_in[2];
  const float* bq  = (const float*)d_in[3];
  const float* Wk  = (const float*)d_in[4];
  const float* bk  = (const float*)d_in[5];
  const float* Wv  = (const float*)d_in[6];
  const float* bv  = (const float*)d_in[7];
  const float* Wcq = (const float*)d_in[8];
  const float* Wck = (const float*)d_in[9];
  const float* gqh = (const float*)d_in[10];
  const float* gkh = (const float*)d_in[11];
  const float* gqc = (const float*)d_in[12];
  const float* gkc = (const float*)d_in[13];

  char* ws = (char*)d_ws;    // ~768 MB available
  unsigned short* hsb   = (unsigned short*)(ws);                   // 33.5 MB
  unsigned short* qhat  = (unsigned short*)(ws + 33554432);        // 33.5 MB
  unsigned short* khat  = (unsigned short*)(ws + 67108864);        // 33.5 MB
  unsigned short* vt    = (unsigned short*)(ws + 100663296);       // 33.5 MB
  unsigned short* probs = (unsigned short*)(ws + 134217728);       // 33.5 MB
  unsigned short* wqb   = (unsigned short*)(ws + 167772160);       // 2 MB  (wqb|wkb|wvb contiguous)
  unsigned short* wkb   = (unsigned short*)(ws + 169869312);       // 2 MB
  unsigned short* wvb   = (unsigned short*)(ws + 171966464);       // 2 MB
  float* up    = (float*)(ws + 174063616);                         // 64 KB
  float* u2    = (float*)(ws + 174129152);                         // 8 KB
  float* ctxq  = (float*)(ws + 174137344);                         // 32 KB
  float* ctxk  = (float*)(ws + 174170112);                         // 32 KB
  float* gq    = (float*)(ws + 174202880);                         // 64 KB
  float* gk    = (float*)(ws + 174268416);                         // 64 KB
  float* scal  = (float*)(ws + 174333952);                         // 256 B

  float* out_attn   = (float*)d_out;                        // [NB,S,H]
  float* out_scores = out_attn + (size_t)MROWS * H;         // [NB,S,S]

  // merged prep (1 dispatch) + combine (1)
  k_prep<<<3649, 256, 0, stream>>>(Wq, Wk, Wv, Wcq, Wck, ctx, gqh, gkh, bq, bk, gqc, gkc,
      wqb, wkb, wvb, up, ctxq, ctxk, scal);
  k_ucombine<<<8, 256, 0, stream>>>(up, u2);
  k_prepass<<<MROWS / 4, 256, 0, stream>>>(hs, u2, scal, hsb, gq, gk);

  // merged QKV projections (M=16384, N=3072, K=1024) — one dispatch
  k_gemm<0><<<dim3(64, 12, 1), 512, 0, stream>>>(hsb, wqb, 1024, 1024, 1024, 0, 0,
      gq, gk, bq, bk, bv, ctxq, ctxk, qhat, khat, vt, nullptr, 0, 1.f);

  // scores = Qhat @ Khat^T * scale (per batch M=N=2048, K=1024), f32 to d_out
  k_gemm<3><<<dim3(8, 8, 8), 512, 0, stream>>>(qhat, khat, 1024, 1024, 1024,
      (long long)S * H, (long long)S * H,
      nullptr, nullptr, nullptr, nullptr, nullptr, nullptr, nullptr,
      nullptr, nullptr, nullptr, out_scores, (long long)S * S, 0.03125f);

  // softmax -> probs bf16
  k_softmax<<<MROWS, 256, 0, stream>>>(out_scores, probs);

  // output = probs @ V (per batch M=2048, N=1024, K=2048; B operand = Vt)
  k_gemm<4><<<dim3(8, 4, 8), 512, 0, stream>>>(probs, vt, 2048, 2048, 2048,
      (long long)S * S, (long long)H * S,
      nullptr, nullptr, nullptr, nullptr, nullptr, nullptr, nullptr,
      nullptr, nullptr, nullptr, out_attn, (long long)S * H, 1.f);
}

// Round 12
// 327.630 us; speedup vs baseline: 1.1402x; 1.0342x over previous
//
#include <hip/hip_runtime.h>
#include <cstdint>
#include <cstddef>

#define H 1024
#define NB 8
#define S 2048
#define MROWS (NB*S)

using short8  = __attribute__((ext_vector_type(8))) short;
using ushort8 = __attribute__((ext_vector_type(8))) unsigned short;
using f32x4   = __attribute__((ext_vector_type(4))) float;

__device__ __forceinline__ unsigned short f2bf(float f){
  union { float f; unsigned int u; } c; c.f = f;
  unsigned int u = c.u;
  return (unsigned short)((u + 0x7fffu + ((u >> 16) & 1u)) >> 16);
}
__device__ __forceinline__ float bf2f(unsigned short b){
  union { unsigned int u; float f; } c; c.u = ((unsigned int)b) << 16;
  return c.f;
}

// ---------------- merged prep kernel ----------------
// blocks [0,3072): W cvt f32->bf16 ; [3072,3136): colproj partials ;
// [3136,3648): ctxproj ; 3648: scalar dots
__global__ __launch_bounds__(256) void k_prep(
    const float* __restrict__ Wq, const float* __restrict__ Wk, const float* __restrict__ Wv,
    const float* __restrict__ Wcq, const float* __restrict__ Wck, const float* __restrict__ ctx,
    const float* __restrict__ gqh, const float* __restrict__ gkh,
    const float* __restrict__ bq, const float* __restrict__ bk,
    const float* __restrict__ gqc, const float* __restrict__ gkc,
    unsigned short* __restrict__ wqb, unsigned short* __restrict__ wkb, unsigned short* __restrict__ wvb,
    float* __restrict__ up, float* __restrict__ ctxq, float* __restrict__ ctxk,
    float* __restrict__ scal)
{
  __shared__ float cs[NB * H];
  const int bid = blockIdx.x;
  const int t = threadIdx.x;
  if (bid < 3072){
    const int y = bid >> 10;
    const int x = bid & 1023;
    const float* src = y == 0 ? Wq : (y == 1 ? Wk : Wv);
    unsigned short* dst = y == 0 ? wqb : (y == 1 ? wkb : wvb);
    const int i = (x * 256 + t) * 4;
    float4 v = *reinterpret_cast<const float4*>(src + i);
    ushort4 o; o.x = f2bf(v.x); o.y = f2bf(v.y); o.z = f2bf(v.z); o.w = f2bf(v.w);
    *reinterpret_cast<ushort4*>(dst + i) = o;
  } else if (bid < 3136){
    const int sub = bid - 3072;
    const int z = sub >> 5;          // 0..1
    const int y = (sub >> 2) & 7;    // 0..7
    const int x = sub & 3;           // 0..3
    const float* W = z ? Wk : Wq;
    const float* g = z ? gkh : gqh;
    const int in = x * 256 + t;
    const int o0 = y * 128;
    float s = 0.f;
    for (int o = 0; o < 128; ++o) s = fmaf(W[(size_t)(o0 + o) * H + in], g[o0 + o], s);
    up[(z * 8 + y) * 1024 + in] = s;
  } else if (bid < 3648){
    const int sub = bid - 3136;
    const int y = sub >> 8;          // 0..1
    const int x = sub & 255;
    const float* W = y ? Wck : Wcq;
    float* out = y ? ctxk : ctxq;
    for (int i = t; i < NB * H; i += 256) cs[i] = ctx[i];
    __syncthreads();
    const int wid = t >> 6, lane = t & 63;
    const int row = x * 4 + wid;
    float a[NB];
    #pragma unroll
    for (int b = 0; b < NB; ++b) a[b] = 0.f;
    for (int i0 = 0; i0 < H; i0 += 64){
      const float w = W[(size_t)row * H + i0 + lane];
      #pragma unroll
      for (int b = 0; b < NB; ++b) a[b] = fmaf(w, cs[b * H + i0 + lane], a[b]);
    }
    #pragma unroll
    for (int b = 0; b < NB; ++b){
      float v = a[b];
      #pragma unroll
      for (int off = 32; off > 0; off >>= 1) v += __shfl_xor(v, off);
      if (lane == 0) out[b * H + row] = v;
    }
  } else {
    // 18 scalar dots, 4 waves
    const int wid = t >> 6, lane = t & 63;
    for (int d = wid; d < 18; d += 4){
      const float *pa, *pb;
      if (d == 0){ pa = bq; pb = gqh; }
      else if (d == 1){ pa = bk; pb = gkh; }
      else if (d < 10){ pa = ctx + (d - 2) * H; pb = gqc; }
      else { pa = ctx + (d - 10) * H; pb = gkc; }
      float s = 0.f;
      for (int i = lane; i < H; i += 64) s = fmaf(pa[i], pb[i], s);
      #pragma unroll
      for (int off = 32; off > 0; off >>= 1) s += __shfl_xor(s, off);
      if (lane == 0) scal[d] = s;
    }
  }
}

__global__ void k_ucombine(const float* __restrict__ up, float* __restrict__ u2){
  int i = blockIdx.x * 256 + threadIdx.x;   // 0..2047
  int z = i >> 10, h = i & 1023;
  float s = 0.f;
  #pragma unroll
  for (int c = 0; c < 8; ++c) s += up[(z * 8 + c) * 1024 + h];
  u2[i] = s;
}

// hs f32 -> bf16, fp32-exact gates per row
__global__ __launch_bounds__(256) void k_prepass(const float* __restrict__ hs,
    const float* __restrict__ u2, const float* __restrict__ scal,
    unsigned short* __restrict__ hsb, float* __restrict__ gq, float* __restrict__ gk){
  const int t = threadIdx.x, wid = t >> 6, lane = t & 63;
  const int row = blockIdx.x * 4 + wid;
  const float* hrow = hs + (size_t)row * H;
  const float* u_q = u2;
  const float* u_k = u2 + 1024;
  unsigned short* orow = hsb + (size_t)row * H;
  float sq = 0.f, sk = 0.f;
  #pragma unroll
  for (int c = 0; c < 4; ++c){
    const int idx = (lane + c * 64) * 4;
    float4 v  = *reinterpret_cast<const float4*>(hrow + idx);
    float4 uq = *reinterpret_cast<const float4*>(u_q + idx);
    float4 uk = *reinterpret_cast<const float4*>(u_k + idx);
    ushort4 o; o.x = f2bf(v.x); o.y = f2bf(v.y); o.z = f2bf(v.z); o.w = f2bf(v.w);
    *reinterpret_cast<ushort4*>(orow + idx) = o;
    sq += v.x*uq.x + v.y*uq.y + v.z*uq.z + v.w*uq.w;
    sk += v.x*uk.x + v.y*uk.y + v.z*uk.z + v.w*uk.w;
  }
  #pragma unroll
  for (int off = 32; off > 0; off >>= 1){
    sq += __shfl_xor(sq, off);
    sk += __shfl_xor(sk, off);
  }
  if (lane == 0){
    const int b = row >> 11;
    gq[row] = 1.f / (1.f + __expf(-(sq + scal[0] + scal[2 + b])));
    gk[row] = 1.f / (1.f + __expf(-(sk + scal[1] + scal[10 + b])));
  }
}

// ---------------- 256x256 GEMM (bt form), R2 single-barrier schedule ----------------
// MODE 0: merged QKV. B spans [wqb|wkb|wvb] (N=3072). Per 1024-col group:
//         group 0/1 -> gated bf16 out (qhat/khat); group 2 -> V transposed (vt)
// MODE 3: scores*scale -> f32 d_out, fused exp -> bf16 probs (oq) + rowsum atomics (rsum)
// MODE 5: PV normalized by rowsum -> f32 out

#define STG(bufi, opi, halfi, koff, P0, P1) \
  do { __builtin_amdgcn_global_load_lds((const __attribute__((address_space(1))) void*)(P0 + (koff)), \
      (__attribute__((address_space(3))) void*)((char*)(&lds[bufi][opi][halfi][0]) + (wid*2+0)*1024), 16, 0, 0); \
    __builtin_amdgcn_global_load_lds((const __attribute__((address_space(1))) void*)(P1 + (koff)), \
      (__attribute__((address_space(3))) void*)((char*)(&lds[bufi][opi][halfi][0]) + (wid*2+1)*1024), 16, 0, 0); } while(0)
#define STG_A(bufi, halfi, koff) STG(bufi, 0, halfi, koff, sA0, sA1)
#define STG_B(bufi, halfi, koff) STG(bufi, 1, halfi, koff, sB0, sB1)

#define DS_A(bufi, ks, mh) \
  do { _Pragma("unroll") for (int m_ = 0; m_ < 4; ++m_){ \
      const int ar_ = wr*128 + ((mh)*4 + m_)*16 + (lane & 15); \
      const int sl_ = (lane >> 4) ^ ((ar_ >> 1) & 3); \
      af[m_] = *reinterpret_cast<const short8*>(&lds[bufi][0][ks][ar_*32 + sl_*8]); } } while(0)
#define DS_B(bufi, ks) \
  do { _Pragma("unroll") for (int n_ = 0; n_ < 4; ++n_){ \
      const int br_ = wc*64 + n_*16 + (lane & 15); \
      const int sl_ = (lane >> 4) ^ ((br_ >> 1) & 3); \
      bf[n_] = *reinterpret_cast<const short8*>(&lds[bufi][1][ks][br_*32 + sl_*8]); } } while(0)
#define MFMA16(mh) \
  do { __builtin_amdgcn_s_setprio(1); \
    _Pragma("unroll") for (int m_ = 0; m_ < 4; ++m_) \
      _Pragma("unroll") for (int n_ = 0; n_ < 4; ++n_) \
        acc[(mh)*4 + m_][n_] = __builtin_amdgcn_mfma_f32_16x16x32_bf16(af[m_], bf[n_], acc[(mh)*4 + m_][n_], 0, 0, 0); \
    __builtin_amdgcn_s_setprio(0); } while(0)
#define VM4() do { asm volatile("s_waitcnt vmcnt(4)" ::: "memory"); } while(0)
#define VM0() do { asm volatile("s_waitcnt vmcnt(0)" ::: "memory"); } while(0)
#define BAR() do { asm volatile("" ::: "memory"); __builtin_amdgcn_s_barrier(); asm volatile("" ::: "memory"); } while(0)

template<int MODE>
__global__ __launch_bounds__(512, 2)
void k_gemm(const unsigned short* __restrict__ A, const unsigned short* __restrict__ B,
            int K, int ldA, int ldB, long long Abatch, long long Bbatch,
            const float* __restrict__ gq, const float* __restrict__ gk,
            const float* __restrict__ bq, const float* __restrict__ bk, const float* __restrict__ bv,
            const float* __restrict__ cq, const float* __restrict__ ck,
            unsigned short* __restrict__ oq, unsigned short* __restrict__ ok, unsigned short* __restrict__ ov,
            float* __restrict__ outf, long long outBatch, float scale, float* __restrict__ rsum)
{
  // [buf][op A=0,B=1][khalf][256 rows * 4 slots * 8 bf16] = 128 KiB total
  __shared__ __align__(16) short lds[2][2][2][8192];

  const int t = threadIdx.x;
  const int wid = t >> 6, lane = t & 63;
  const int wr = wid >> 2, wc = wid & 3;      // 2 x 4 wave grid
  const int bz = blockIdx.z;
  const unsigned short* Ab = A + (size_t)bz * (size_t)Abatch;
  const unsigned short* Bb = B + (size_t)bz * (size_t)Bbatch;
  const int row0 = blockIdx.x * 256;
  const int col0 = blockIdx.y * 256;

  const int c0 = (wid*2 + 0)*64 + lane;
  const int c1 = (wid*2 + 1)*64 + lane;
  const int r0s = c0 >> 2, r1s = c1 >> 2;
  const int kc0 = (c0 & 3) ^ ((r0s >> 1) & 3);   // pre-swizzled global k-chunk (involution)
  const int kc1 = (c1 & 3) ^ ((r1s >> 1) & 3);
  const unsigned short* sA0 = Ab + (size_t)(row0 + r0s) * (size_t)ldA + kc0*8;
  const unsigned short* sA1 = Ab + (size_t)(row0 + r1s) * (size_t)ldA + kc1*8;
  const unsigned short* sB0 = Bb + (size_t)(col0 + r0s) * (size_t)ldB + kc0*8;
  const unsigned short* sB1 = Bb + (size_t)(col0 + r1s) * (size_t)ldB + kc1*8;

  f32x4 acc[8][4] = {};
  short8 af[4], bf[4];

  STG_A(0, 0, 0); STG_B(0, 0, 0); STG_A(0, 1, 32); STG_B(0, 1, 32);
  VM0(); BAR();

  const int niter = K >> 7;       // 2 K-tiles (of 64) per iteration
  for (int it = 0; it < niter; ++it){
    const int t1k = (it*2 + 1) << 6;
    const int t2k = (it*2 + 2) << 6;
    const bool more = (it + 1 < niter);
    // R2 schedule: {DS || STG ; MFMA ; [vmcnt] ; BAR} — one barrier per phase
    DS_A(0, 0, 0); DS_B(0, 0); STG_A(1, 0, t1k);      MFMA16(0);                              BAR();
    DS_A(0, 0, 1);             STG_B(1, 0, t1k);      MFMA16(1); VM4();                       BAR();
    DS_A(0, 1, 0); DS_B(0, 1); STG_A(1, 1, t1k + 32); MFMA16(0);                              BAR();
    DS_A(0, 1, 1);             STG_B(1, 1, t1k + 32); MFMA16(1); if (more) { VM4(); } else { VM0(); } BAR();
    DS_A(1, 0, 0); DS_B(1, 0); if (more) { STG_A(0, 0, t2k); }      MFMA16(0);                BAR();
    DS_A(1, 0, 1);             if (more) { STG_B(0, 0, t2k); }      MFMA16(1); if (more) { VM4(); } BAR();
    DS_A(1, 1, 0); DS_B(1, 1); if (more) { STG_A(0, 1, t2k + 32); } MFMA16(0);                BAR();
    DS_A(1, 1, 1);             if (more) { STG_B(0, 1, t2k + 32); } MFMA16(1); if (more) { VM4(); } BAR();
  }

  // ---- epilogues ---- (C/D layout m89: col=lane&15, row=(lane>>4)*4+reg)
  if constexpr (MODE == 0){
    const int which = col0 >> 10;        // 0=Q 1=K 2=V
    const int lcol  = col0 & 1023;
    if (which < 2){
      const float* gate = which ? gk : gq;
      const float* bias = which ? bk : bq;
      const float* ctxv = which ? ck : cq;
      unsigned short* outb = which ? ok : oq;
      unsigned short* tp = (unsigned short*)lds;          // [128][264]
      float* gl = (float*)((char*)lds + 69632);
      float* bl = gl + 256;
      float* cl = bl + 256;
      const int b = row0 >> 11;
      __syncthreads();
      if (t < 256){
        gl[t] = gate[row0 + t];
        bl[t] = bias[lcol + t];
        cl[t] = ctxv[b * H + lcol + t];
      }
      __syncthreads();
      #pragma unroll
      for (int ci = 0; ci < 2; ++ci){
        if (ci) __syncthreads();
        if (wr == ci){
          #pragma unroll
          for (int mi = 0; mi < 8; ++mi)
            #pragma unroll
            for (int r = 0; r < 4; ++r){
              const int lr = mi*16 + (lane >> 4)*4 + r;
              const float g = gl[ci*128 + lr];
              #pragma unroll
              for (int n = 0; n < 4; ++n){
                const int lc = wc*64 + n*16 + (lane & 15);
                const float q = acc[mi][n][r] + bl[lc];
                tp[lr*264 + lc] = f2bf((1.f - g) * q + g * cl[lc]);
              }
            }
        }
        __syncthreads();
        const int rr = t & 127;
        const int cc = (t >> 7) * 64;
        const unsigned short* srcp = tp + rr*264 + cc;
        unsigned short* dst = outb + (size_t)(row0 + ci*128 + rr) * H + lcol + cc;
        #pragma unroll
        for (int i = 0; i < 64; i += 8)
          *reinterpret_cast<ushort8*>(dst + i) = *reinterpret_cast<const ushort8*>(srcp + i);
      }
    } else {
      // V transposed store path
      unsigned short* tp = (unsigned short*)lds;   // [128 h][136 s]
      const int bb = row0 >> 11;
      const int s0 = row0 & (S - 1);
      #pragma unroll
      for (int ci = 0; ci < 2; ++ci)
        #pragma unroll
        for (int cj = 0; cj < 2; ++cj){
          __syncthreads();
          if (wr == ci && (wc >> 1) == cj){
            const int lc0 = (wc & 1) * 64;
            #pragma unroll
            for (int mi = 0; mi < 8; ++mi)
              #pragma unroll
              for (int n = 0; n < 4; ++n)
                #pragma unroll
                for (int r = 0; r < 4; ++r){
                  const int lr = mi*16 + (lane >> 4)*4 + r;           // s
                  const int lc = lc0 + n*16 + (lane & 15);            // h
                  tp[lc*136 + lr] = f2bf(acc[mi][n][r] + bv[lcol + cj*128 + lc]);
                }
          }
          __syncthreads();
          const int hh = t & 127;
          const int sc = (t >> 7) * 32;
          const unsigned short* srcp = tp + hh*136 + sc;
          unsigned short* vout = ov + (size_t)bb * H * S + (size_t)(lcol + cj*128 + hh) * S
                                    + (size_t)(s0 + ci*128 + sc);
          #pragma unroll
          for (int i2 = 0; i2 < 32; i2 += 8)
            *reinterpret_cast<ushort8*>(vout + i2) = *reinterpret_cast<const ushort8*>(srcp + i2);
        }
    }
  } else if constexpr (MODE == 3){
    // scores f32 -> outf; pe = exp(min(val,80)) bf16 -> oq (probs, unnormalized);
    // per-row sums -> rsum via LDS reduce + one global atomicAdd per row.
    float* rowacc = (float*)lds;   // 256 floats
    __syncthreads();
    if (t < 256) rowacc[t] = 0.f;
    __syncthreads();
    #pragma unroll
    for (int mi = 0; mi < 8; ++mi)
      #pragma unroll
      for (int r = 0; r < 4; ++r){
        const int lr = wr*128 + mi*16 + (lane >> 4)*4 + r;
        const int grow = row0 + lr;
        float psum = 0.f;
        #pragma unroll
        for (int n = 0; n < 4; ++n){
          const int gcol = col0 + wc*64 + n*16 + (lane & 15);
          const float val = acc[mi][n][r] * scale;
          outf[(size_t)bz * (size_t)outBatch + (size_t)grow * S + gcol] = val;
          const float pe = __expf(fminf(val, 80.f));     // clamp: no overflow possible
          const unsigned short pb = f2bf(pe);
          oq[(size_t)bz * (size_t)outBatch + (size_t)grow * S + gcol] = pb;
          psum += bf2f(pb);                               // sum the ROUNDED values
        }
        #pragma unroll
        for (int off = 1; off < 16; off <<= 1) psum += __shfl_xor(psum, off);
        if ((lane & 15) == 0) atomicAdd(&rowacc[lr], psum);
      }
    __syncthreads();
    if (t < 256) atomicAdd(&rsum[bz * S + row0 + t], rowacc[t]);
  } else {
    // MODE 5: PV normalized by rowsum
    float* rs = (float*)lds;
    __syncthreads();
    if (t < 256) rs[t] = 1.f / fmaxf(rsum[bz * S + row0 + t], 1e-35f);
    __syncthreads();
    #pragma unroll
    for (int mi = 0; mi < 8; ++mi)
      #pragma unroll
      for (int r = 0; r < 4; ++r){
        const int lr = wr*128 + mi*16 + (lane >> 4)*4 + r;
        const float inv = rs[lr];
        #pragma unroll
        for (int n = 0; n < 4; ++n){
          const int gcol = col0 + wc*64 + n*16 + (lane & 15);
          outf[(size_t)bz * (size_t)outBatch + (size_t)(row0 + lr) * H + gcol] = acc[mi][n][r] * inv;
        }
      }
  }
}

// ---------------- launch ----------------
extern "C" void kernel_launch(void* const* d_in, const int* in_sizes, int n_in,
                              void* d_out, int out_size, void* d_ws, size_t ws_size,
                              hipStream_t stream) {
  const float* hs  = (const float*)d_in[0];
  const float* ctx = (const float*)d_in[1];
  const float* Wq  = (const float*)d_in[2];
  const float* bq  = (const float*)d_in[3];
  const float* Wk  = (const float*)d_in[4];
  const float* bk  = (const float*)d_in[5];
  const float* Wv  = (const float*)d_in[6];
  const float* bv  = (const float*)d_in[7];
  const float* Wcq = (const float*)d_in[8];
  const float* Wck = (const float*)d_in[9];
  const float* gqh = (const float*)d_in[10];
  const float* gkh = (const float*)d_in[11];
  const float* gqc = (const float*)d_in[12];
  const float* gkc = (const float*)d_in[13];

  char* ws = (char*)d_ws;    // ~768 MB available
  // NOTE: probs is [NB,S,S] bf16 = 67,108,864 B — R6/R11 NaNs were probs
  // overflowing a 33.5 MB slot and clobbering live accumulators above it.
  unsigned short* hsb   = (unsigned short*)(ws);                   // 33.5 MB
  unsigned short* qhat  = (unsigned short*)(ws + 33554432);        // 33.5 MB
  unsigned short* khat  = (unsigned short*)(ws + 67108864);        // 33.5 MB
  unsigned short* vt    = (unsigned short*)(ws + 100663296);       // 33.5 MB
  unsigned short* probs = (unsigned short*)(ws + 134217728);       // 67.1 MB  [NB,S,S]
  unsigned short* wqb   = (unsigned short*)(ws + 201326592);       // 2 MB (wqb|wkb|wvb contiguous)
  unsigned short* wkb   = (unsigned short*)(ws + 203423744);       // 2 MB
  unsigned short* wvb   = (unsigned short*)(ws + 205520896);       // 2 MB
  float* up    = (float*)(ws + 207618048);                         // 64 KB
  float* u2    = (float*)(ws + 207683584);                         // 8 KB
  float* ctxq  = (float*)(ws + 207691776);                         // 32 KB
  float* ctxk  = (float*)(ws + 207724544);                         // 32 KB
  float* gq    = (float*)(ws + 207757312);                         // 64 KB
  float* gk    = (float*)(ws + 207822848);                         // 64 KB
  float* scal  = (float*)(ws + 207888384);                         // 256 B
  float* rsum  = (float*)(ws + 207888640);                         // 64 KB (per-row exp sums)

  float* out_attn   = (float*)d_out;                        // [NB,S,H]
  float* out_scores = out_attn + (size_t)MROWS * H;         // [NB,S,S]

  // zero rowsum accumulators (64 KB)
  hipMemsetAsync(rsum, 0, MROWS * sizeof(float), stream);

  // merged prep (1 dispatch) + combine (1)
  k_prep<<<3649, 256, 0, stream>>>(Wq, Wk, Wv, Wcq, Wck, ctx, gqh, gkh, bq, bk, gqc, gkc,
      wqb, wkb, wvb, up, ctxq, ctxk, scal);
  k_ucombine<<<8, 256, 0, stream>>>(up, u2);
  k_prepass<<<MROWS / 4, 256, 0, stream>>>(hs, u2, scal, hsb, gq, gk);

  // merged QKV projections (M=16384, N=3072, K=1024) — one dispatch
  k_gemm<0><<<dim3(64, 12, 1), 512, 0, stream>>>(hsb, wqb, 1024, 1024, 1024, 0, 0,
      gq, gk, bq, bk, bv, ctxq, ctxk, qhat, khat, vt, nullptr, 0, 1.f, nullptr);

  // scores + fused exp/probs/rowsum (per batch M=N=2048, K=1024)
  k_gemm<3><<<dim3(8, 8, 8), 512, 0, stream>>>(qhat, khat, 1024, 1024, 1024,
      (long long)S * H, (long long)S * H,
      nullptr, nullptr, nullptr, nullptr, nullptr, nullptr, nullptr,
      probs, nullptr, nullptr, out_scores, (long long)S * S, 0.03125f, rsum);

  // output = (probs @ V) / rowsum (per batch M=2048, N=1024, K=2048; B operand = Vt)
  k_gemm<5><<<dim3(8, 4, 8), 512, 0, stream>>>(probs, vt, 2048, 2048, 2048,
      (long long)S * S, (long long)H * S,
      nullptr, nullptr, nullptr, nullptr, nullptr, nullptr, nullptr,
      nullptr, nullptr, nullptr, out_attn, (long long)S * H, 1.f, rsum);
}